// Round 11
// baseline (1959.282 us; speedup 1.0000x reference)
//
#include <hip/hip_runtime.h>
#include <hip/hip_bf16.h>
#include <cstdint>
#include <cstddef>

#define BATCH 2
#define SEQ   4096
#define DIM   1024
#define NHEAD 16
#define HDIM  64
#define NBLK  64
#define NMID  62
#define NRAND 3
#define NLAYER 4
#define FFDIM 4096
#define ROWS  (BATCH*SEQ)   // 8192
#define KSPL  8             // key splits for global attention
#define QKVLD (3*DIM)       // fused qkv row stride
#define WLAYER (12*1024*1024)  // shorts per layer in hoisted weight buffer

using f32x4 = __attribute__((ext_vector_type(4))) float;
using s16x8 = __attribute__((ext_vector_type(8))) short;
using s16x4 = __attribute__((ext_vector_type(4))) short;

__device__ inline float bf2f(short s) {
    unsigned u = ((unsigned)(unsigned short)s) << 16;
    union { unsigned u; float f; } cv; cv.u = u; return cv.f;
}
__device__ inline short f2bf(float f) {
    union { float f; unsigned u; } cv; cv.f = f;
    unsigned u = cv.u;
    unsigned r = (u + 0x7fffu + ((u >> 16) & 1u)) >> 16;  // RNE
    return (short)r;
}
// exact-formula tanh-gelu via hardware __expf (~1e-6 rel err, << bf16 ulp)
__device__ inline float gelu_f(float x) {
    float u = 0.7978845608028654f * (x + 0.044715f * x * x * x);
    float a = fabsf(u);
    float th = 1.f - 2.f / (1.f + __expf(2.f * a));
    th = copysignf(th, u);
    return 0.5f * x * (1.f + th);
}

// async global->LDS, 16B per lane; LDS dest is wave-uniform base + lane*16B
__device__ inline void gload16(const short* g, short* l) {
    __builtin_amdgcn_global_load_lds(
        (const __attribute__((address_space(1))) void*)g,
        (__attribute__((address_space(3))) void*)l,
        16, 0, 0);
}

// ---------------------------------------------------------------- embedding
__global__ __launch_bounds__(256) void embed_kernel(
    const int* __restrict__ ids, const float* __restrict__ emb, float* __restrict__ x)
{
    int row = blockIdx.x;
    int id  = ids[row];
    ((float4*)x)[(size_t)row * 256 + threadIdx.x] =
        ((const float4*)emb)[(size_t)id * 256 + threadIdx.x];
}

// ---------------------------------------------------------------- neg mask
__global__ __launch_bounds__(256) void neg_kernel(
    const int* __restrict__ mask, float* __restrict__ neg)
{
    int i = blockIdx.x * 256 + threadIdx.x;
    if (i < ROWS) neg[i] = (1.f - (float)mask[i]) * -1e9f;
}

// ---------------------------------------------------------------- bias pack (qkv, all layers)
__global__ __launch_bounds__(256) void biaspack_kernel(
    const float* __restrict__ bq, const float* __restrict__ bk,
    const float* __restrict__ bv, float* __restrict__ b3)
{
    int i = blockIdx.x * 256 + threadIdx.x;   // 0..3071
    int l = blockIdx.y;
    float v = (i < DIM) ? bq[l * DIM + i]
            : (i < 2 * DIM) ? bk[l * DIM + i - DIM]
            : bv[l * DIM + i - 2 * DIM];
    b3[(size_t)l * QKVLD + i] = v;
}

// ---------------------------------------------------------------- layernorm (row=1024)
template<int OUTBF>
__global__ __launch_bounds__(256) void ln_kernel(
    const float* __restrict__ x, const float* __restrict__ g,
    const float* __restrict__ bia, void* __restrict__ out)
{
    __shared__ float s1[4], s2[4];
    int row = blockIdx.x, t = threadIdx.x;
    const float* xr = x + (size_t)row * DIM;
    float4 v = ((const float4*)xr)[t];
    float s = v.x + v.y + v.z + v.w;
    #pragma unroll
    for (int o = 32; o > 0; o >>= 1) s += __shfl_xor(s, o, 64);
    if ((t & 63) == 0) s1[t >> 6] = s;
    __syncthreads();
    float mu = (s1[0] + s1[1] + s1[2] + s1[3]) * (1.f / DIM);
    float dx = v.x - mu, dy = v.y - mu, dz = v.z - mu, dw = v.w - mu;
    float q = dx*dx + dy*dy + dz*dz + dw*dw;
    #pragma unroll
    for (int o = 32; o > 0; o >>= 1) q += __shfl_xor(q, o, 64);
    if ((t & 63) == 0) s2[t >> 6] = q;
    __syncthreads();
    float var = (s2[0] + s2[1] + s2[2] + s2[3]) * (1.f / DIM);
    float rs  = rsqrtf(var + 1e-5f);
    float4 gg = ((const float4*)g)[t];
    float4 bb = ((const float4*)bia)[t];
    float o0 = dx * rs * gg.x + bb.x;
    float o1 = dy * rs * gg.y + bb.y;
    float o2 = dz * rs * gg.z + bb.z;
    float o3 = dw * rs * gg.w + bb.w;
    if (OUTBF) {
        s16x4 ov = { f2bf(o0), f2bf(o1), f2bf(o2), f2bf(o3) };
        ((s16x4*)out)[(size_t)row * (DIM/4) + t] = ov;
    } else {
        float4 ov = { o0, o1, o2, o3 };
        ((float4*)out)[(size_t)row * (DIM/4) + t] = ov;
    }
}

// ---------------------------------------------------------------- weight transpose + bf16 (batched)
__device__ inline void wconv_body(const float* __restrict__ W, short* __restrict__ Wt,
                                  int K, int N)
{
    __shared__ float tile[32][33];
    int k0 = blockIdx.x * 32, n0 = blockIdx.y * 32;
    int t = threadIdx.x;
    int r = t >> 3, c = (t & 7) * 4;
    float4 v = *(const float4*)(W + (size_t)(k0 + r) * N + n0 + c);
    tile[r][c+0] = v.x; tile[r][c+1] = v.y; tile[r][c+2] = v.z; tile[r][c+3] = v.w;
    __syncthreads();
    s16x4 ov;
    #pragma unroll
    for (int jj = 0; jj < 4; ++jj) ov[jj] = f2bf(tile[c + jj][r]);
    *(s16x4*)(Wt + (size_t)(n0 + r) * K + k0 + c) = ov;
}

__global__ __launch_bounds__(256) void wconv4_kernel(
    const float* __restrict__ Wq, const float* __restrict__ Wk,
    const float* __restrict__ Wv, const float* __restrict__ Wo,
    short* __restrict__ wt4)
{
    int z = blockIdx.z, l = z >> 2, m = z & 3;
    const float* W = (m == 0 ? Wq : m == 1 ? Wk : m == 2 ? Wv : Wo) + (size_t)l * DIM * DIM;
    short* Wt = wt4 + (size_t)l * WLAYER + (size_t)m * 1024 * 1024;
    wconv_body(W, Wt, DIM, DIM);
}

__global__ __launch_bounds__(256) void wconvff_kernel(
    const float* __restrict__ W, short* __restrict__ wt4,
    int K, int N, size_t dstOff)
{
    int l = blockIdx.z;
    wconv_body(W + (size_t)l * DIM * FFDIM, wt4 + (size_t)l * WLAYER + dstOff, K, N);
}

// ---------------------------------------------------------------- V transpose (per head)
__global__ __launch_bounds__(256) void vtrans_kernel(
    const short* __restrict__ qkv, short* __restrict__ vT)
{
    __shared__ short tile[64][66];
    const int sb = blockIdx.x, h = blockIdx.y, b = blockIdx.z;
    const int t = threadIdx.x;
    {
        int row = t >> 2, c0 = (t & 3) * 16;
        const short* src = qkv + 2 * DIM + (size_t)(b * SEQ + sb * 64 + row) * QKVLD + h * HDIM + c0;
        s16x8 a0 = ((const s16x8*)src)[0];
        s16x8 a1 = ((const s16x8*)src)[1];
        #pragma unroll
        for (int i = 0; i < 8; ++i) { tile[row][c0 + i] = a0[i]; tile[row][c0 + 8 + i] = a1[i]; }
    }
    __syncthreads();
    {
        int d = t >> 2, k0 = (t & 3) * 16;
        s16x8 o0, o1;
        #pragma unroll
        for (int i = 0; i < 8; ++i) { o0[i] = tile[k0 + i][d]; o1[i] = tile[k0 + 8 + i][d]; }
        short* dst = vT + (size_t)((b * NHEAD + h) * HDIM + d) * SEQ + sb * 64 + k0;
        ((s16x8*)dst)[0] = o0;
        ((s16x8*)dst)[1] = o1;
    }
}

// ---------------------------------------------------------------- GEMM 256x256, 8-wave, 2-phase dbuf (R6-proven, 1774us config)
// C[M,N] = A[M,K](bf16) * Bt[N,K]^T(bf16) + bias
// EPI 0: bf16 ; 1: bf16+gelu ; 2: fp32 + residual add ; 3: fp32 raw partial (split-K z)
// Prefetch STAGE(next) issued BEFORE compute; single __syncthreads per K-tile drains.
// Linear LDS dest + pre-swizzled global source; reads apply matching XOR (rule 21).
template<int EPI>
__global__ __launch_bounds__(512) void gemm256_kernel(
    const short* __restrict__ A, const short* __restrict__ Bt,
    const float* __restrict__ bias, const float* __restrict__ resid,
    void* __restrict__ Cout, int M, int N, int K, int klen)
{
    __shared__ short As[2][256 * 64];   // 2 x 32KB
    __shared__ short Bs[2][256 * 64];   // 2 x 32KB  -> 128KB total
    const int t = threadIdx.x;
    const int m0 = blockIdx.x * 256, n0 = blockIdx.y * 256;
    const int lane = t & 63, wave = t >> 6;
    const int wm = wave >> 2, wn = wave & 3;         // 2 x 4 wave grid
    const int lrow = lane >> 3;                      // 0..7 in 8-row chunk
    const int lksw = ((lane & 7) ^ lrow) * 8;        // pre-swizzled source k-offset

    f32x4 acc[8][4];
    #pragma unroll
    for (int m = 0; m < 8; ++m)
        #pragma unroll
        for (int n = 0; n < 4; ++n)
            acc[m][n] = f32x4{0.f, 0.f, 0.f, 0.f};

    auto STAGE = [&](int side, int kt) {
        #pragma unroll
        for (int c = 0; c < 4; ++c) {
            int chunk = wave + c * 8;                // 0..31 (8 rows each)
            int row = chunk * 8 + lrow;              // 0..255
            gload16(A  + (size_t)(m0 + row) * K + kt + lksw, &As[side][chunk * 512]);
            gload16(Bt + (size_t)(n0 + row) * K + kt + lksw, &Bs[side][chunk * 512]);
        }
    };

    const int k0 = blockIdx.z * klen, kend = k0 + klen;
    STAGE(0, k0);
    __syncthreads();

    int cur = 0;
    for (int kt = k0; kt < kend; kt += 64) {
        if (kt + 64 < kend) STAGE(cur ^ 1, kt + 64);   // prefetch (in flight across compute)
        const short* Ac = As[cur];
        const short* Bc = Bs[cur];
        #pragma unroll
        for (int kk = 0; kk < 2; ++kk) {
            const int cb = kk * 64 + (lane >> 4) * 16;
            s16x8 bfr[4];
            #pragma unroll
            for (int n = 0; n < 4; ++n) {
                int rB = wn * 64 + n * 16 + (lane & 15);
                bfr[n] = *(const s16x8*)((const char*)Bc + rB * 128 + (cb ^ ((rB & 7) << 4)));
            }
            #pragma unroll
            for (int mq = 0; mq < 4; ++mq) {
                s16x8 af[2];
                #pragma unroll
                for (int i = 0; i < 2; ++i) {
                    int rA = wm * 128 + mq * 32 + i * 16 + (lane & 15);
                    af[i] = *(const s16x8*)((const char*)Ac + rA * 128 + (cb ^ ((rA & 7) << 4)));
                }
                #pragma unroll
                for (int i = 0; i < 2; ++i)
                    #pragma unroll
                    for (int n = 0; n < 4; ++n)
                        acc[mq * 2 + i][n] = __builtin_amdgcn_mfma_f32_16x16x32_bf16(
                            af[i], bfr[n], acc[mq * 2 + i][n], 0, 0, 0);
            }
        }
        __syncthreads();   // drains prefetch (landed during 64 MFMA) + joins reads
        cur ^= 1;
    }

    const int rbase = m0 + wm * 128 + ((lane >> 4) << 2);
    const int cbase = n0 + wn * 64 + (lane & 15);
    #pragma unroll
    for (int m = 0; m < 8; ++m) {
        #pragma unroll
        for (int n = 0; n < 4; ++n) {
            #pragma unroll
            for (int j = 0; j < 4; ++j) {
                int row = rbase + m * 16 + j;
                int col = cbase + n * 16;
                size_t idx = (size_t)row * N + col;
                float val = acc[m][n][j];
                if (EPI == 3) {
                    ((float*)Cout)[(size_t)blockIdx.z * ((size_t)M * N) + idx] = val;
                } else if (EPI == 2) {
                    ((float*)Cout)[idx] = val + bias[col] + resid[idx];
                } else {
                    val += bias[col];
                    if (EPI == 1) val = gelu_f(val);
                    ((short*)Cout)[idx] = f2bf(val);
                }
            }
        }
    }
}

// ---------------------------------------------------------------- FF2 reduce + fused LayerNorm
// MODE 0: x = x + p0 + p1 + bias; xn(bf16) = LN(x; g,b)   [next layer's ln1]
// MODE 1: v = x + p0 + p1 + bias; xn(fp32) = LN(v; g,b)   [final LN]
template<int MODE>
__global__ __launch_bounds__(256) void kred_ln_kernel(
    const float* __restrict__ part, const float* __restrict__ bias,
    const float* __restrict__ g, const float* __restrict__ bvec,
    float* __restrict__ x, void* __restrict__ xn)
{
    __shared__ float s1[4], s2[4];
    const size_t MN = (size_t)ROWS * DIM;
    const int row = blockIdx.x, t = threadIdx.x;
    size_t idx = (size_t)row * DIM + t * 4;
    float4 p0 = *(const float4*)(part + idx);
    float4 p1 = *(const float4*)(part + MN + idx);
    float4 bb = *(const float4*)(bias + t * 4);
    float4 xv = *(const float4*)(x + idx);
    float4 v = { xv.x + p0.x + p1.x + bb.x,
                 xv.y + p0.y + p1.y + bb.y,
                 xv.z + p0.z + p1.z + bb.z,
                 xv.w + p0.w + p1.w + bb.w };
    if (MODE == 0) *(float4*)(x + idx) = v;

    float s = v.x + v.y + v.z + v.w;
    #pragma unroll
    for (int o = 32; o > 0; o >>= 1) s += __shfl_xor(s, o, 64);
    if ((t & 63) == 0) s1[t >> 6] = s;
    __syncthreads();
    float mu = (s1[0] + s1[1] + s1[2] + s1[3]) * (1.f / DIM);
    float dx = v.x - mu, dy = v.y - mu, dz = v.z - mu, dw = v.w - mu;
    float q = dx*dx + dy*dy + dz*dz + dw*dw;
    #pragma unroll
    for (int o = 32; o > 0; o >>= 1) q += __shfl_xor(q, o, 64);
    if ((t & 63) == 0) s2[t >> 6] = q;
    __syncthreads();
    float var = (s2[0] + s2[1] + s2[2] + s2[3]) * (1.f / DIM);
    float rs  = rsqrtf(var + 1e-5f);
    float4 gg = ((const float4*)g)[t];
    float4 b2 = ((const float4*)bvec)[t];
    float o0 = dx * rs * gg.x + b2.x;
    float o1 = dy * rs * gg.y + b2.y;
    float o2 = dz * rs * gg.z + b2.z;
    float o3 = dw * rs * gg.w + b2.w;
    if (MODE == 0) {
        s16x4 ov = { f2bf(o0), f2bf(o1), f2bf(o2), f2bf(o3) };
        ((s16x4*)xn)[(size_t)row * (DIM/4) + t] = ov;
    } else {
        float4 ov = { o0, o1, o2, o3 };
        ((float4*)xn)[(size_t)row * (DIM/4) + t] = ov;
    }
}

// ================================================================ MFMA attention
__device__ inline void attn_tile_mfma(
    const short* __restrict__ kglob, const short* __restrict__ vtglob,
    const float* __restrict__ negp, int kld,
    short* Ks, short* Vs, float* kmask,
    const s16x8* qfrag, f32x4* o, float& mr, float& lsum)
{
    const int t = threadIdx.x;
    const int lane = t & 63;
    const int q15 = lane & 15, g = lane >> 4;
    const int sw = (lane & 7) << 4;

    {   // stage K [k][d] and V^T [d][k], swizzled
        int row = t >> 2, c0 = (t & 3) * 16;
        int rsw = (row & 7) << 4;
        const short* ksrc = kglob + (size_t)row * kld + c0;
        s16x8 a0 = ((const s16x8*)ksrc)[0];
        s16x8 a1 = ((const s16x8*)ksrc)[1];
        char* kdst = (char*)Ks + row * 128;
        *(s16x8*)(kdst + ((c0 * 2)      ^ rsw)) = a0;
        *(s16x8*)(kdst + ((c0 * 2 + 16) ^ rsw)) = a1;
        const short* vsrc = vtglob + (size_t)row * SEQ + c0;
        s16x8 b0 = ((const s16x8*)vsrc)[0];
        s16x8 b1 = ((const s16x8*)vsrc)[1];
        char* vdst = (char*)Vs + row * 128;
        *(s16x8*)(vdst + ((c0 * 2)      ^ rsw)) = b0;
        *(s16x8*)(vdst + ((c0 * 2 + 16) ^ rsw)) = b1;
        if (t < 16) ((float4*)kmask)[t] = ((const float4*)negp)[t];
    }
    __syncthreads();

    f32x4 s[4];
    #pragma unroll
    for (int f = 0; f < 4; ++f) s[f] = f32x4{0.f, 0.f, 0.f, 0.f};
    #pragma unroll
    for (int ch = 0; ch < 2; ++ch) {
        #pragma unroll
        for (int f = 0; f < 4; ++f) {
            s16x8 kf = *(const s16x8*)((const char*)Ks + (16 * f + q15) * 128 + ((ch * 64 + g * 16) ^ sw));
            s[f] = __builtin_amdgcn_mfma_f32_16x16x32_bf16(kf, qfrag[ch], s[f], 0, 0, 0);
        }
    }

    float p[4][4];
    float mt = -1e30f;
    #pragma unroll
    for (int f = 0; f < 4; ++f) {
        float4 km = ((const float4*)kmask)[f * 4 + g];
        #pragma unroll
        for (int j = 0; j < 4; ++j) {
            float val = s[f][j] * 0.125f + ((const float*)&km)[j];
            p[f][j] = val;
            mt = fmaxf(mt, val);
        }
    }
    mt = fmaxf(mt, __shfl_xor(mt, 16, 64));
    mt = fmaxf(mt, __shfl_xor(mt, 32, 64));
    float mn = fmaxf(mr, mt);
    float psum = 0.f;
    #pragma unroll
    for (int f = 0; f < 4; ++f)
        #pragma unroll
        for (int j = 0; j < 4; ++j) {
            float e = __expf(p[f][j] - mn);
            p[f][j] = e;
            psum += e;
        }
    psum += __shfl_xor(psum, 16, 64);
    psum += __shfl_xor(psum, 32, 64);
    float fc = __expf(mr - mn);
    mr = mn;
    lsum = lsum * fc + psum;
    #pragma unroll
    for (int dt = 0; dt < 4; ++dt)
        #pragma unroll
        for (int j = 0; j < 4; ++j) o[dt][j] *= fc;

    unsigned pk[4][2];
    #pragma unroll
    for (int f = 0; f < 4; ++f)
        #pragma unroll
        for (int pp = 0; pp < 2; ++pp)
            pk[f][pp] = ((unsigned)(unsigned short)f2bf(p[f][2 * pp + 1]) << 16)
                      |  (unsigned)(unsigned short)f2bf(p[f][2 * pp]);

    const int bsel = (lane >> 4) & 1, asel = (lane >> 5) & 1;
    #pragma unroll
    for (int c = 0; c < 2; ++c) {
        union { s16x8 v; int u[4]; } pb;
        #pragma unroll
        for (int w = 0; w < 4; ++w) {
            int src = q15 + 16 * (2 * bsel + (w >> 1));
            int lo = __shfl((int)pk[2 * c][w & 1], src, 64);
            int hi = __shfl((int)pk[2 * c + 1][w & 1], src, 64);
            pb.u[w] = asel ? hi : lo;
        }
        #pragma unroll
        for (int dt = 0; dt < 4; ++dt) {
            s16x8 vf = *(const s16x8*)((const char*)Vs + (16 * dt + q15) * 128 + ((c * 64 + g * 16) ^ sw));
            o[dt] = __builtin_amdgcn_mfma_f32_16x16x32_bf16(vf, pb.v, o[dt], 0, 0, 0);
        }
    }
    __syncthreads();
}

__device__ inline void stage_q64_swz(const short* __restrict__ qglob, int qld, short* Qs)
{
    int t = threadIdx.x;
    int row = t >> 2, c0 = (t & 3) * 16;
    int rsw = (row & 7) << 4;
    const short* src = qglob + (size_t)row * qld + c0;
    s16x8 a0 = ((const s16x8*)src)[0];
    s16x8 a1 = ((const s16x8*)src)[1];
    char* dst = (char*)Qs + row * 128;
    *(s16x8*)(dst + ((c0 * 2)      ^ rsw)) = a0;
    *(s16x8*)(dst + ((c0 * 2 + 16) ^ rsw)) = a1;
}

// ---------------------------------------------------------------- middle blocks
__global__ __launch_bounds__(256) void attn_middle_mfma(
    const short* __restrict__ qkv, const short* __restrict__ vT,
    const float* __restrict__ neg, const int* __restrict__ rand_attn, short* __restrict__ ctx)
{
    __shared__ short Qs[64 * 64];
    __shared__ short Ks[64 * 64];
    __shared__ short Vs[64 * 64];
    __shared__ float kmask[64];

    const int j = blockIdx.x, h = blockIdx.y, b = blockIdx.z;
    const int n = j + 1;
    const int t = threadIdx.x;
    const int lane = t & 63, wave = t >> 6;
    const int q15 = lane & 15, g = lane >> 4;
    const int sw = (lane & 7) << 4;

    stage_q64_swz(qkv + (size_t)(b * SEQ + n * 64) * QKVLD + h * HDIM, QKVLD, Qs);
    __syncthreads();

    s16x8 qfrag[2];
    {
        int qrow = wave * 16 + q15;
        #pragma unroll
        for (int ch = 0; ch < 2; ++ch)
            qfrag[ch] = *(const s16x8*)((const char*)Qs + qrow * 128 + ((ch * 64 + g * 16) ^ sw));
    }

    int kbl[8];
    kbl[0] = n - 1; kbl[1] = n; kbl[2] = n + 1; kbl[3] = 0; kbl[4] = NBLK - 1;
    {
        const int* ra = rand_attn + ((size_t)h * NMID + j) * NRAND;
        kbl[5] = ra[0]; kbl[6] = ra[1]; kbl[7] = ra[2];
    }

    f32x4 o[4];
    #pragma unroll
    for (int dt = 0; dt < 4; ++dt) o[dt] = f32x4{0.f, 0.f, 0.f, 0.f};
    float mr = -1e30f, lsum = 0.f;

    const short* kbase  = qkv + DIM + (size_t)b * SEQ * QKVLD + h * HDIM;
    const short* vtbase = vT + (size_t)(b * NHEAD + h) * HDIM * SEQ;
    const float* negb   = neg + (size_t)b * SEQ;

    #pragma unroll 1
    for (int ib = 0; ib < 8; ++ib) {
        int kbn = kbl[ib];
        attn_tile_mfma(kbase + (size_t)kbn * 64 * QKVLD, vtbase + kbn * 64,
                       negb + kbn * 64, QKVLD, Ks, Vs, kmask, qfrag, o, mr, lsum);
    }

    float inv = 1.f / lsum;
    short* obase = ctx + (size_t)(b * SEQ + n * 64 + wave * 16 + q15) * DIM + h * HDIM;
    #pragma unroll
    for (int dt = 0; dt < 4; ++dt) {
        s16x4 ov;
        #pragma unroll
        for (int jj = 0; jj < 4; ++jj) ov[jj] = f2bf(o[dt][jj] * inv);
        *(s16x4*)(obase + dt * 16 + g * 4) = ov;
    }
}

// ---------------------------------------------------------------- global blocks, split-K
__global__ __launch_bounds__(256) void attn_global_mfma(
    const short* __restrict__ qkv, const short* __restrict__ vT,
    const float* __restrict__ neg, float* __restrict__ part)
{
    __shared__ short Qs[64 * 64];
    __shared__ short Ks[64 * 64];
    __shared__ short Vs[64 * 64];
    __shared__ float kmask[64];

    const int qb = blockIdx.x >> 3, ks = blockIdx.x & 7;
    const int h = blockIdx.y, b = blockIdx.z;
    const int tok0 = qb ? (SEQ - 64) : 0;
    const int t = threadIdx.x;
    const int lane = t & 63, wave = t >> 6;
    const int q15 = lane & 15, g = lane >> 4;
    const int sw = (lane & 7) << 4;

    stage_q64_swz(qkv + (size_t)(b * SEQ + tok0) * QKVLD + h * HDIM, QKVLD, Qs);
    __syncthreads();

    s16x8 qfrag[2];
    {
        int qrow = wave * 16 + q15;
        #pragma unroll
        for (int ch = 0; ch < 2; ++ch)
            qfrag[ch] = *(const s16x8*)((const char*)Qs + qrow * 128 + ((ch * 64 + g * 16) ^ sw));
    }

    f32x4 o[4];
    #pragma unroll
    for (int dt = 0; dt < 4; ++dt) o[dt] = f32x4{0.f, 0.f, 0.f, 0.f};
    float mr = -1e30f, lsum = 0.f;

    const short* kbase  = qkv + DIM + (size_t)b * SEQ * QKVLD + h * HDIM;
    const short* vtbase = vT + (size_t)(b * NHEAD + h) * HDIM * SEQ;
    const float* negb   = neg + (size_t)b * SEQ;

    #pragma unroll 1
    for (int ib = 0; ib < 8; ++ib) {
        int kbn = ks * 8 + ib;
        attn_tile_mfma(kbase + (size_t)kbn * 64 * QKVLD, vtbase + kbn * 64,
                       negb + kbn * 64, QKVLD, Ks, Vs, kmask, qfrag, o, mr, lsum);
    }

    float* pbase = part + ((size_t)(((b * NHEAD + h) * 2 + qb) * KSPL + ks)) * 4224;
    int qrow = wave * 16 + q15;
    #pragma unroll
    for (int dt = 0; dt < 4; ++dt)
        *(f32x4*)(pbase + qrow * 64 + dt * 16 + g * 4) = o[dt];
    if (g == 0) { pbase[4096 + qrow] = mr; pbase[4160 + qrow] = lsum; }
}

// ---------------------------------------------------------------- merge global partials
__global__ __launch_bounds__(256) void attn_greduce(
    const float* __restrict__ part, short* __restrict__ ctx)
{
    const int qb = blockIdx.x, h = blockIdx.y, b = blockIdx.z;
    const int tok0 = qb ? (SEQ - 64) : 0;
    const int t = threadIdx.x;
    const int qq = t >> 2, d0 = (t & 3) * 16;
    const float* base = part + ((size_t)(((b * NHEAD + h) * 2 + qb) * KSPL)) * 4224;

    float m = -1e30f;
    #pragma unroll 1
    for (int s = 0; s < KSPL; ++s)
        m = fmaxf(m, base[(size_t)s * 4224 + 4096 + qq]);
    float L = 0.f;
    float acc[16];
    #pragma unroll
    for (int i = 0; i < 16; ++i) acc[i] = 0.f;
    #pragma unroll 1
    for (int s = 0; s < KSPL; ++s) {
        const float* bp = base + (size_t)s * 4224;
        float w = __expf(bp[4096 + qq] - m);
        L += w * bp[4160 + qq];
        const float4* row = (const float4*)(bp + qq * 64 + d0);
        #pragma unroll
        for (int v4 = 0; v4 < 4; ++v4) {
            float4 val = row[v4];
            acc[v4 * 4 + 0] = fmaf(w, val.x, acc[v4 * 4 + 0]);
            acc[v4 * 4 + 1] = fmaf(w, val.y, acc[v4 * 4 + 1]);
            acc[v4 * 4 + 2] = fmaf(w, val.z, acc[v4 * 4 + 2]);
            acc[v4 * 4 + 3] = fmaf(w, val.w, acc[v4 * 4 + 3]);
        }
    }
    float inv = 1.f / L;
    short* dst = ctx + (size_t)(b * SEQ + tok0 + qq) * DIM + h * HDIM + d0;
    s16x8 o0, o1;
    #pragma unroll
    for (int i = 0; i < 8; ++i) { o0[i] = f2bf(acc[i] * inv); o1[i] = f2bf(acc[8 + i] * inv); }
    ((s16x8*)dst)[0] = o0;
    ((s16x8*)dst)[1] = o1;
}

// ---------------------------------------------------------------- column mean, stage 1
__global__ __launch_bounds__(256) void colsum1_kernel(
    const float* __restrict__ xln, float* __restrict__ partial)
{
    const int ch = blockIdx.x, b = blockIdx.y, t = threadIdx.x;
    const float* base = xln + ((size_t)b * SEQ + ch * 32) * DIM + t * 4;
    float4 acc = {0.f, 0.f, 0.f, 0.f};
    #pragma unroll 4
    for (int r = 0; r < 32; ++r) {
        float4 v = *(const float4*)(base + (size_t)r * DIM);
        acc.x += v.x; acc.y += v.y; acc.z += v.z; acc.w += v.w;
    }
    *(float4*)(partial + ((size_t)(b * 128 + ch)) * DIM + t * 4) = acc;
}

// ---------------------------------------------------------------- column mean, stage 2
__global__ __launch_bounds__(256) void colsum2_kernel(
    const float* __restrict__ partial, float* __restrict__ feats)
{
    const int b = blockIdx.x, t = threadIdx.x;
    float4 acc = {0.f, 0.f, 0.f, 0.f};
    #pragma unroll 1
    for (int ch = 0; ch < 128; ++ch) {
        float4 v = *(const float4*)(partial + ((size_t)(b * 128 + ch)) * DIM + t * 4);
        acc.x += v.x; acc.y += v.y; acc.z += v.z; acc.w += v.w;
    }
    const float is = 1.f / SEQ;
    float4 o = { acc.x * is, acc.y * is, acc.z * is, acc.w * is };
    *(float4*)(feats + (size_t)b * DIM + t * 4) = o;
}

// ---------------------------------------------------------------- normalize + project
__global__ __launch_bounds__(256) void head_kernel(
    const float* __restrict__ feats, const float* __restrict__ projW,
    const float* __restrict__ projb, float* __restrict__ out)
{
    __shared__ float f[DIM];
    __shared__ float slots[4];
    int b = blockIdx.x, t = threadIdx.x;
    float ss = 0.f;
    for (int i = t; i < DIM; i += 256) {
        float vv = feats[b * DIM + i];
        f[i] = vv;
        ss += vv * vv;
    }
    #pragma unroll
    for (int o = 32; o > 0; o >>= 1) ss += __shfl_xor(ss, o, 64);
    if ((t & 63) == 0) slots[t >> 6] = ss;
    __syncthreads();
    float nrm = sqrtf(slots[0] + slots[1] + slots[2] + slots[3]);
    float inv = 1.f / fmaxf(nrm, 1e-12f);
    for (int o = t; o < 512; o += 256) {
        float acc = 0.f;
        for (int d = 0; d < DIM; ++d)
            acc = fmaf(f[d], projW[(size_t)d * 512 + o], acc);
        out[b * 512 + o] = acc * inv + projb[o];
    }
}

// ---------------------------------------------------------------- launch
extern "C" void kernel_launch(void* const* d_in, const int* in_sizes, int n_in,
                              void* d_out, int out_size, void* d_ws, size_t ws_size,
                              hipStream_t stream)
{
    (void)in_sizes; (void)n_in; (void)out_size; (void)ws_size;
    const int*   ids   = (const int*)d_in[0];
    const int*   amask = (const int*)d_in[1];
    const int*   rnd   = (const int*)d_in[2];
    const float* emb   = (const float*)d_in[3];
    const float* Wq    = (const float*)d_in[4];
    const float* bq    = (const float*)d_in[5];
    const float* Wk    = (const float*)d_in[6];
    const float* bk    = (const float*)d_in[7];
    const float* Wv    = (const float*)d_in[8];
    const float* bv    = (const float*)d_in[9];
    const float* Wo    = (const float*)d_in[10];
    const float* bo    = (const float*)d_in[11];
    const float* ln1g  = (const float*)d_in[12];
    const float* ln1b  = (const float*)d_in[13];
    const float* W1    = (const float*)d_in[14];
    const float* b1    = (const float*)d_in[15];
    const float* W2    = (const float*)d_in[16];
    const float* b2    = (const float*)d_in[17];
    const float* ln2g  = (const float*)d_in[18];
    const float* ln2b  = (const float*)d_in[19];
    const float* lnfg  = (const float*)d_in[20];
    const float* lnfb  = (const float*)d_in[21];
    const float* projW = (const float*)d_in[22];
    const float* projb = (const float*)d_in[23];
    float* out = (float*)d_out;

    char* ws = (char*)d_ws;
    size_t off = 0;
    float* x    = (float*)(ws + off); off += (size_t)ROWS * DIM * 4;
    float* xn_f = (float*)(ws + off);
    short* xn_b = (short*)(ws + off); off += (size_t)ROWS * DIM * 4;
    short* qkv  = (short*)(ws + off); off += (size_t)ROWS * QKVLD * 2;   // 48 MB
    short* vT   = (short*)(ws + off); off += (size_t)ROWS * DIM * 2;     // 16 MB
    short* ctxb = (short*)(ws + off); off += (size_t)ROWS * DIM * 2;
    short* ffb  = (short*)(ws + off); off += (size_t)ROWS * FFDIM * 2;
    short* wt4  = (short*)(ws + off); off += (size_t)NLAYER * WLAYER * 2; // 96 MB
    float* neg  = (float*)(ws + off); off += (size_t)ROWS * 4;
    float* bias3= (float*)(ws + off); off += (size_t)NLAYER * QKVLD * 4;
    float* feats= (float*)(ws + off); off += (size_t)BATCH * DIM * 4;
    float* part = (float*)(ws + off); off += (size_t)BATCH * NHEAD * 2 * KSPL * 4224 * 4;
    float* cpart= (float*)(ws + off); off += (size_t)BATCH * 128 * DIM * 4;
    // FF2 split-K fp32 partials (2 x 32 MB) alias qkv+vT (dead by FF2 time)
    float* ff2p = (float*)qkv;

    embed_kernel<<<ROWS, 256, 0, stream>>>(ids, emb, x);
    neg_kernel<<<(ROWS + 255) / 256, 256, 0, stream>>>(amask, neg);

    // batched weight conversions: 3 dispatches + 1 biaspack
    wconv4_kernel<<<dim3(DIM/32, DIM/32, NLAYER*4), 256, 0, stream>>>(Wq, Wk, Wv, Wo, wt4);
    wconvff_kernel<<<dim3(DIM/32, FFDIM/32, NLAYER), 256, 0, stream>>>(W1, wt4, DIM, FFDIM, (size_t)4*1024*1024);
    wconvff_kernel<<<dim3(FFDIM/32, DIM/32, NLAYER), 256, 0, stream>>>(W2, wt4, FFDIM, DIM, (size_t)8*1024*1024);
    biaspack_kernel<<<dim3(QKVLD/256, NLAYER), 256, 0, stream>>>(bq, bk, bv, bias3);

    for (int l = 0; l < NLAYER; ++l) {
        short* wq3 = wt4 + (size_t)l * WLAYER;
        short* wo  = wq3 + 3 * 1024 * 1024;
        short* w1t = wo  + 1024 * 1024;
        short* w2t = w1t + 4 * 1024 * 1024;

        if (l == 0)
            ln_kernel<1><<<ROWS, 256, 0, stream>>>(x, ln1g, ln1b, xn_b);

        gemm256_kernel<0><<<dim3(ROWS/256, QKVLD/256), 512, 0, stream>>>(xn_b, wq3, bias3 + (size_t)l*QKVLD, nullptr, qkv, ROWS, QKVLD, DIM, DIM);

        vtrans_kernel<<<dim3(SEQ/64, NHEAD, BATCH), 256, 0, stream>>>(qkv, vT);

        attn_global_mfma<<<dim3(2 * KSPL, NHEAD, BATCH), 256, 0, stream>>>(qkv, vT, neg, part);
        attn_middle_mfma<<<dim3(NMID, NHEAD, BATCH), 256, 0, stream>>>(qkv, vT, neg, rnd, ctxb);
        attn_greduce<<<dim3(2, NHEAD, BATCH), 256, 0, stream>>>(part, ctxb);

        gemm256_kernel<2><<<dim3(ROWS/256, DIM/256), 512, 0, stream>>>(ctxb, wo, bo + l*DIM, x, x, ROWS, DIM, DIM, DIM);

        ln_kernel<1><<<ROWS, 256, 0, stream>>>(x, ln2g + l * DIM, ln2b + l * DIM, xn_b);

        gemm256_kernel<1><<<dim3(ROWS/256, FFDIM/256), 512, 0, stream>>>(xn_b, w1t, b1 + l*FFDIM, nullptr, ffb, ROWS, FFDIM, DIM, DIM);
        gemm256_kernel<3><<<dim3(ROWS/256, DIM/256, 2), 512, 0, stream>>>(ffb, w2t, nullptr, nullptr, ff2p, ROWS, DIM, FFDIM, FFDIM/2);

        if (l < NLAYER - 1)
            kred_ln_kernel<0><<<ROWS, 256, 0, stream>>>(ff2p, b2 + l*DIM, ln1g + (l+1)*DIM, ln1b + (l+1)*DIM, x, xn_b);
        else
            kred_ln_kernel<1><<<ROWS, 256, 0, stream>>>(ff2p, b2 + l*DIM, lnfg, lnfb, x, xn_f);
    }

    colsum1_kernel<<<dim3(SEQ/32, BATCH), 256, 0, stream>>>(xn_f, cpart);
    colsum2_kernel<<<BATCH, 256, 0, stream>>>(cpart, feats);
    head_kernel<<<BATCH, 256, 0, stream>>>(feats, projW, projb, out);
}

// Round 12
// 1906.358 us; speedup vs baseline: 1.0278x; 1.0278x over previous
//
#include <hip/hip_runtime.h>
#include <hip/hip_bf16.h>
#include <cstdint>
#include <cstddef>

#define BATCH 2
#define SEQ   4096
#define DIM   1024
#define NHEAD 16
#define HDIM  64
#define NBLK  64
#define NMID  62
#define NRAND 3
#define NLAYER 4
#define FFDIM 4096
#define ROWS  (BATCH*SEQ)   // 8192
#define KSPL  8             // key splits for global attention
#define QKVLD (3*DIM)       // fused qkv row stride
#define WLAYER (12*1024*1024)  // shorts per layer in hoisted weight buffer

using f32x4 = __attribute__((ext_vector_type(4))) float;
using s16x8 = __attribute__((ext_vector_type(8))) short;
using s16x4 = __attribute__((ext_vector_type(4))) short;

__device__ inline float bf2f(short s) {
    unsigned u = ((unsigned)(unsigned short)s) << 16;
    union { unsigned u; float f; } cv; cv.u = u; return cv.f;
}
__device__ inline short f2bf(float f) {
    union { float f; unsigned u; } cv; cv.f = f;
    unsigned u = cv.u;
    unsigned r = (u + 0x7fffu + ((u >> 16) & 1u)) >> 16;  // RNE
    return (short)r;
}
// exact-formula tanh-gelu via hardware __expf (~1e-6 rel err, << bf16 ulp)
__device__ inline float gelu_f(float x) {
    float u = 0.7978845608028654f * (x + 0.044715f * x * x * x);
    float a = fabsf(u);
    float th = 1.f - 2.f / (1.f + __expf(2.f * a));
    th = copysignf(th, u);
    return 0.5f * x * (1.f + th);
}

// async global->LDS, 16B per lane; LDS dest is wave-uniform base + lane*16B
__device__ inline void gload16(const short* g, short* l) {
    __builtin_amdgcn_global_load_lds(
        (const __attribute__((address_space(1))) void*)g,
        (__attribute__((address_space(3))) void*)l,
        16, 0, 0);
}

// ---------------------------------------------------------------- embedding
__global__ __launch_bounds__(256) void embed_kernel(
    const int* __restrict__ ids, const float* __restrict__ emb, float* __restrict__ x)
{
    int row = blockIdx.x;
    int id  = ids[row];
    ((float4*)x)[(size_t)row * 256 + threadIdx.x] =
        ((const float4*)emb)[(size_t)id * 256 + threadIdx.x];
}

// ---------------------------------------------------------------- neg mask
__global__ __launch_bounds__(256) void neg_kernel(
    const int* __restrict__ mask, float* __restrict__ neg)
{
    int i = blockIdx.x * 256 + threadIdx.x;
    if (i < ROWS) neg[i] = (1.f - (float)mask[i]) * -1e9f;
}

// ---------------------------------------------------------------- bias pack (qkv, all layers)
__global__ __launch_bounds__(256) void biaspack_kernel(
    const float* __restrict__ bq, const float* __restrict__ bk,
    const float* __restrict__ bv, float* __restrict__ b3)
{
    int i = blockIdx.x * 256 + threadIdx.x;   // 0..3071
    int l = blockIdx.y;
    float v = (i < DIM) ? bq[l * DIM + i]
            : (i < 2 * DIM) ? bk[l * DIM + i - DIM]
            : bv[l * DIM + i - 2 * DIM];
    b3[(size_t)l * QKVLD + i] = v;
}

// ---------------------------------------------------------------- layernorm (row=1024)
template<int OUTBF>
__global__ __launch_bounds__(256) void ln_kernel(
    const float* __restrict__ x, const float* __restrict__ g,
    const float* __restrict__ bia, void* __restrict__ out)
{
    __shared__ float s1[4], s2[4];
    int row = blockIdx.x, t = threadIdx.x;
    const float* xr = x + (size_t)row * DIM;
    float4 v = ((const float4*)xr)[t];
    float s = v.x + v.y + v.z + v.w;
    #pragma unroll
    for (int o = 32; o > 0; o >>= 1) s += __shfl_xor(s, o, 64);
    if ((t & 63) == 0) s1[t >> 6] = s;
    __syncthreads();
    float mu = (s1[0] + s1[1] + s1[2] + s1[3]) * (1.f / DIM);
    float dx = v.x - mu, dy = v.y - mu, dz = v.z - mu, dw = v.w - mu;
    float q = dx*dx + dy*dy + dz*dz + dw*dw;
    #pragma unroll
    for (int o = 32; o > 0; o >>= 1) q += __shfl_xor(q, o, 64);
    if ((t & 63) == 0) s2[t >> 6] = q;
    __syncthreads();
    float var = (s2[0] + s2[1] + s2[2] + s2[3]) * (1.f / DIM);
    float rs  = rsqrtf(var + 1e-5f);
    float4 gg = ((const float4*)g)[t];
    float4 bb = ((const float4*)bia)[t];
    float o0 = dx * rs * gg.x + bb.x;
    float o1 = dy * rs * gg.y + bb.y;
    float o2 = dz * rs * gg.z + bb.z;
    float o3 = dw * rs * gg.w + bb.w;
    if (OUTBF) {
        s16x4 ov = { f2bf(o0), f2bf(o1), f2bf(o2), f2bf(o3) };
        ((s16x4*)out)[(size_t)row * (DIM/4) + t] = ov;
    } else {
        float4 ov = { o0, o1, o2, o3 };
        ((float4*)out)[(size_t)row * (DIM/4) + t] = ov;
    }
}

// ---------------------------------------------------------------- weight transpose + bf16 (batched)
__device__ inline void wconv_body(const float* __restrict__ W, short* __restrict__ Wt,
                                  int K, int N)
{
    __shared__ float tile[32][33];
    int k0 = blockIdx.x * 32, n0 = blockIdx.y * 32;
    int t = threadIdx.x;
    int r = t >> 3, c = (t & 7) * 4;
    float4 v = *(const float4*)(W + (size_t)(k0 + r) * N + n0 + c);
    tile[r][c+0] = v.x; tile[r][c+1] = v.y; tile[r][c+2] = v.z; tile[r][c+3] = v.w;
    __syncthreads();
    s16x4 ov;
    #pragma unroll
    for (int jj = 0; jj < 4; ++jj) ov[jj] = f2bf(tile[c + jj][r]);
    *(s16x4*)(Wt + (size_t)(n0 + r) * K + k0 + c) = ov;
}

__global__ __launch_bounds__(256) void wconv4_kernel(
    const float* __restrict__ Wq, const float* __restrict__ Wk,
    const float* __restrict__ Wv, const float* __restrict__ Wo,
    short* __restrict__ wt4)
{
    int z = blockIdx.z, l = z >> 2, m = z & 3;
    const float* W = (m == 0 ? Wq : m == 1 ? Wk : m == 2 ? Wv : Wo) + (size_t)l * DIM * DIM;
    short* Wt = wt4 + (size_t)l * WLAYER + (size_t)m * 1024 * 1024;
    wconv_body(W, Wt, DIM, DIM);
}

__global__ __launch_bounds__(256) void wconvff_kernel(
    const float* __restrict__ W, short* __restrict__ wt4,
    int K, int N, size_t dstOff)
{
    int l = blockIdx.z;
    wconv_body(W + (size_t)l * DIM * FFDIM, wt4 + (size_t)l * WLAYER + dstOff, K, N);
}

// ---------------------------------------------------------------- V transpose (per head)
__global__ __launch_bounds__(256) void vtrans_kernel(
    const short* __restrict__ qkv, short* __restrict__ vT)
{
    __shared__ short tile[64][66];
    const int sb = blockIdx.x, h = blockIdx.y, b = blockIdx.z;
    const int t = threadIdx.x;
    {
        int row = t >> 2, c0 = (t & 3) * 16;
        const short* src = qkv + 2 * DIM + (size_t)(b * SEQ + sb * 64 + row) * QKVLD + h * HDIM + c0;
        s16x8 a0 = ((const s16x8*)src)[0];
        s16x8 a1 = ((const s16x8*)src)[1];
        #pragma unroll
        for (int i = 0; i < 8; ++i) { tile[row][c0 + i] = a0[i]; tile[row][c0 + 8 + i] = a1[i]; }
    }
    __syncthreads();
    {
        int d = t >> 2, k0 = (t & 3) * 16;
        s16x8 o0, o1;
        #pragma unroll
        for (int i = 0; i < 8; ++i) { o0[i] = tile[k0 + i][d]; o1[i] = tile[k0 + 8 + i][d]; }
        short* dst = vT + (size_t)((b * NHEAD + h) * HDIM + d) * SEQ + sb * 64 + k0;
        ((s16x8*)dst)[0] = o0;
        ((s16x8*)dst)[1] = o1;
    }
}

// ---------------------------------------------------------------- GEMM 256x256, 8-wave, 2-phase dbuf (R6/R7-proven)
// C[M,N] = A[M,K](bf16) * Bt[N,K]^T(bf16) + bias
// EPI 0: bf16 ; 1: bf16+gelu ; 3: fp32 raw partial (split-K via blockIdx.z)
template<int EPI>
__global__ __launch_bounds__(512) void gemm256_kernel(
    const short* __restrict__ A, const short* __restrict__ Bt,
    const float* __restrict__ bias, void* __restrict__ Cout,
    int M, int N, int K, int klen)
{
    __shared__ short As[2][256 * 64];   // 2 x 32KB
    __shared__ short Bs[2][256 * 64];   // 2 x 32KB  -> 128KB total
    const int t = threadIdx.x;
    const int m0 = blockIdx.x * 256, n0 = blockIdx.y * 256;
    const int lane = t & 63, wave = t >> 6;
    const int wm = wave >> 2, wn = wave & 3;         // 2 x 4 wave grid
    const int lrow = lane >> 3;                      // 0..7 in 8-row chunk
    const int lksw = ((lane & 7) ^ lrow) * 8;        // pre-swizzled source k-offset

    f32x4 acc[8][4];
    #pragma unroll
    for (int m = 0; m < 8; ++m)
        #pragma unroll
        for (int n = 0; n < 4; ++n)
            acc[m][n] = f32x4{0.f, 0.f, 0.f, 0.f};

    auto STAGE = [&](int side, int kt) {
        #pragma unroll
        for (int c = 0; c < 4; ++c) {
            int chunk = wave + c * 8;                // 0..31 (8 rows each)
            int row = chunk * 8 + lrow;              // 0..255
            gload16(A  + (size_t)(m0 + row) * K + kt + lksw, &As[side][chunk * 512]);
            gload16(Bt + (size_t)(n0 + row) * K + kt + lksw, &Bs[side][chunk * 512]);
        }
    };

    const int k0 = blockIdx.z * klen, kend = k0 + klen;
    STAGE(0, k0);
    __syncthreads();

    int cur = 0;
    for (int kt = k0; kt < kend; kt += 64) {
        if (kt + 64 < kend) STAGE(cur ^ 1, kt + 64);   // prefetch (in flight across compute)
        const short* Ac = As[cur];
        const short* Bc = Bs[cur];
        #pragma unroll
        for (int kk = 0; kk < 2; ++kk) {
            const int cb = kk * 64 + (lane >> 4) * 16;
            s16x8 bfr[4];
            #pragma unroll
            for (int n = 0; n < 4; ++n) {
                int rB = wn * 64 + n * 16 + (lane & 15);
                bfr[n] = *(const s16x8*)((const char*)Bc + rB * 128 + (cb ^ ((rB & 7) << 4)));
            }
            #pragma unroll
            for (int mq = 0; mq < 4; ++mq) {
                s16x8 af[2];
                #pragma unroll
                for (int i = 0; i < 2; ++i) {
                    int rA = wm * 128 + mq * 32 + i * 16 + (lane & 15);
                    af[i] = *(const s16x8*)((const char*)Ac + rA * 128 + (cb ^ ((rA & 7) << 4)));
                }
                #pragma unroll
                for (int i = 0; i < 2; ++i)
                    #pragma unroll
                    for (int n = 0; n < 4; ++n)
                        acc[mq * 2 + i][n] = __builtin_amdgcn_mfma_f32_16x16x32_bf16(
                            af[i], bfr[n], acc[mq * 2 + i][n], 0, 0, 0);
            }
        }
        __syncthreads();   // drains prefetch (landed during 64 MFMA) + joins reads
        cur ^= 1;
    }

    const int rbase = m0 + wm * 128 + ((lane >> 4) << 2);
    const int cbase = n0 + wn * 64 + (lane & 15);
    #pragma unroll
    for (int m = 0; m < 8; ++m) {
        #pragma unroll
        for (int n = 0; n < 4; ++n) {
            #pragma unroll
            for (int j = 0; j < 4; ++j) {
                int row = rbase + m * 16 + j;
                int col = cbase + n * 16;
                size_t idx = (size_t)row * N + col;
                float val = acc[m][n][j];
                if (EPI == 3) {
                    ((float*)Cout)[(size_t)blockIdx.z * ((size_t)M * N) + idx] = val;
                } else {
                    val += bias[col];
                    if (EPI == 1) val = gelu_f(val);
                    ((short*)Cout)[idx] = f2bf(val);
                }
            }
        }
    }
}

// ---------------------------------------------------------------- GEMM 128x128 (O-proj; 512 blocks = 2/CU)
// EPI 2: out fp32 + bias + residual add
template<int EPI>
__global__ __launch_bounds__(256) void gemm_kernel(
    const short* __restrict__ A, const short* __restrict__ Bt,
    const float* __restrict__ bias, const float* __restrict__ resid,
    void* __restrict__ Cout, int M, int N, int K, int klen)
{
    __shared__ short As[128 * 64];
    __shared__ short Bs[128 * 64];
    const int t = threadIdx.x;
    const int m0 = blockIdx.x * 128, n0 = blockIdx.y * 128;
    const int lane = t & 63, wave = t >> 6;
    const int wr = (wave >> 1) * 64, wc = (wave & 1) * 64;
    const int lrow = lane >> 3;
    const int lksw = ((lane & 7) ^ lrow) * 8;

    f32x4 acc[4][4];
    #pragma unroll
    for (int m = 0; m < 4; ++m)
        #pragma unroll
        for (int n = 0; n < 4; ++n)
            acc[m][n] = f32x4{0.f, 0.f, 0.f, 0.f};

    const int k0 = blockIdx.z * klen;
    for (int kt = k0; kt < k0 + klen; kt += 64) {
        #pragma unroll
        for (int c = 0; c < 4; ++c) {
            int chunk = wave * 4 + c;
            int row = chunk * 8 + lrow;
            gload16(A  + (size_t)(m0 + row) * K + kt + lksw, As + chunk * 512);
            gload16(Bt + (size_t)(n0 + row) * K + kt + lksw, Bs + chunk * 512);
        }
        asm volatile("s_waitcnt vmcnt(0)" ::: "memory");
        __syncthreads();
        #pragma unroll
        for (int kk = 0; kk < 2; ++kk) {
            s16x8 af[4], bfr[4];
            int cb = kk * 64 + (lane >> 4) * 16;
            #pragma unroll
            for (int i = 0; i < 4; ++i) {
                int rA = wr + i * 16 + (lane & 15);
                af[i]  = *(const s16x8*)((const char*)As + rA * 128 + (cb ^ ((rA & 7) << 4)));
                int rB = wc + i * 16 + (lane & 15);
                bfr[i] = *(const s16x8*)((const char*)Bs + rB * 128 + (cb ^ ((rB & 7) << 4)));
            }
            #pragma unroll
            for (int m = 0; m < 4; ++m)
                #pragma unroll
                for (int n = 0; n < 4; ++n)
                    acc[m][n] = __builtin_amdgcn_mfma_f32_16x16x32_bf16(
                        af[m], bfr[n], acc[m][n], 0, 0, 0);
        }
        __syncthreads();
    }

    const int rbase = m0 + wr + ((lane >> 4) << 2);
    const int cbase = n0 + wc + (lane & 15);
    #pragma unroll
    for (int m = 0; m < 4; ++m) {
        #pragma unroll
        for (int n = 0; n < 4; ++n) {
            #pragma unroll
            for (int j = 0; j < 4; ++j) {
                int row = rbase + m * 16 + j;
                int col = cbase + n * 16;
                size_t idx = (size_t)row * N + col;
                float val = acc[m][n][j] + bias[col];
                if (EPI == 1) val = gelu_f(val);
                if (EPI == 2) ((float*)Cout)[idx] = val + resid[idx];
                else          ((short*)Cout)[idx] = f2bf(val);
            }
        }
    }
}

// ---------------------------------------------------------------- FF2 reduce + fused LayerNorm
// MODE 0: x = x + p0 + p1 + bias; xn(bf16) = LN(x; g,b)   [next layer's ln1]
// MODE 1: v = x + p0 + p1 + bias; xn(fp32) = LN(v; g,b)   [final LN]
template<int MODE>
__global__ __launch_bounds__(256) void kred_ln_kernel(
    const float* __restrict__ part, const float* __restrict__ bias,
    const float* __restrict__ g, const float* __restrict__ bvec,
    float* __restrict__ x, void* __restrict__ xn)
{
    __shared__ float s1[4], s2[4];
    const size_t MN = (size_t)ROWS * DIM;
    const int row = blockIdx.x, t = threadIdx.x;
    size_t idx = (size_t)row * DIM + t * 4;
    float4 p0 = *(const float4*)(part + idx);
    float4 p1 = *(const float4*)(part + MN + idx);
    float4 bb = *(const float4*)(bias + t * 4);
    float4 xv = *(const float4*)(x + idx);
    float4 v = { xv.x + p0.x + p1.x + bb.x,
                 xv.y + p0.y + p1.y + bb.y,
                 xv.z + p0.z + p1.z + bb.z,
                 xv.w + p0.w + p1.w + bb.w };
    if (MODE == 0) *(float4*)(x + idx) = v;

    float s = v.x + v.y + v.z + v.w;
    #pragma unroll
    for (int o = 32; o > 0; o >>= 1) s += __shfl_xor(s, o, 64);
    if ((t & 63) == 0) s1[t >> 6] = s;
    __syncthreads();
    float mu = (s1[0] + s1[1] + s1[2] + s1[3]) * (1.f / DIM);
    float dx = v.x - mu, dy = v.y - mu, dz = v.z - mu, dw = v.w - mu;
    float q = dx*dx + dy*dy + dz*dz + dw*dw;
    #pragma unroll
    for (int o = 32; o > 0; o >>= 1) q += __shfl_xor(q, o, 64);
    if ((t & 63) == 0) s2[t >> 6] = q;
    __syncthreads();
    float var = (s2[0] + s2[1] + s2[2] + s2[3]) * (1.f / DIM);
    float rs  = rsqrtf(var + 1e-5f);
    float4 gg = ((const float4*)g)[t];
    float4 b2 = ((const float4*)bvec)[t];
    float o0 = dx * rs * gg.x + b2.x;
    float o1 = dy * rs * gg.y + b2.y;
    float o2 = dz * rs * gg.z + b2.z;
    float o3 = dw * rs * gg.w + b2.w;
    if (MODE == 0) {
        s16x4 ov = { f2bf(o0), f2bf(o1), f2bf(o2), f2bf(o3) };
        ((s16x4*)xn)[(size_t)row * (DIM/4) + t] = ov;
    } else {
        float4 ov = { o0, o1, o2, o3 };
        ((float4*)xn)[(size_t)row * (DIM/4) + t] = ov;
    }
}

// ================================================================ MFMA attention
__device__ inline void attn_tile_mfma(
    const short* __restrict__ kglob, const short* __restrict__ vtglob,
    const float* __restrict__ negp, int kld,
    short* Ks, short* Vs, float* kmask,
    const s16x8* qfrag, f32x4* o, float& mr, float& lsum)
{
    const int t = threadIdx.x;
    const int lane = t & 63;
    const int q15 = lane & 15, g = lane >> 4;
    const int sw = (lane & 7) << 4;

    {   // stage K [k][d] and V^T [d][k], swizzled
        int row = t >> 2, c0 = (t & 3) * 16;
        int rsw = (row & 7) << 4;
        const short* ksrc = kglob + (size_t)row * kld + c0;
        s16x8 a0 = ((const s16x8*)ksrc)[0];
        s16x8 a1 = ((const s16x8*)ksrc)[1];
        char* kdst = (char*)Ks + row * 128;
        *(s16x8*)(kdst + ((c0 * 2)      ^ rsw)) = a0;
        *(s16x8*)(kdst + ((c0 * 2 + 16) ^ rsw)) = a1;
        const short* vsrc = vtglob + (size_t)row * SEQ + c0;
        s16x8 b0 = ((const s16x8*)vsrc)[0];
        s16x8 b1 = ((const s16x8*)vsrc)[1];
        char* vdst = (char*)Vs + row * 128;
        *(s16x8*)(vdst + ((c0 * 2)      ^ rsw)) = b0;
        *(s16x8*)(vdst + ((c0 * 2 + 16) ^ rsw)) = b1;
        if (t < 16) ((float4*)kmask)[t] = ((const float4*)negp)[t];
    }
    __syncthreads();

    f32x4 s[4];
    #pragma unroll
    for (int f = 0; f < 4; ++f) s[f] = f32x4{0.f, 0.f, 0.f, 0.f};
    #pragma unroll
    for (int ch = 0; ch < 2; ++ch) {
        #pragma unroll
        for (int f = 0; f < 4; ++f) {
            s16x8 kf = *(const s16x8*)((const char*)Ks + (16 * f + q15) * 128 + ((ch * 64 + g * 16) ^ sw));
            s[f] = __builtin_amdgcn_mfma_f32_16x16x32_bf16(kf, qfrag[ch], s[f], 0, 0, 0);
        }
    }

    float p[4][4];
    float mt = -1e30f;
    #pragma unroll
    for (int f = 0; f < 4; ++f) {
        float4 km = ((const float4*)kmask)[f * 4 + g];
        #pragma unroll
        for (int j = 0; j < 4; ++j) {
            float val = s[f][j] * 0.125f + ((const float*)&km)[j];
            p[f][j] = val;
            mt = fmaxf(mt, val);
        }
    }
    mt = fmaxf(mt, __shfl_xor(mt, 16, 64));
    mt = fmaxf(mt, __shfl_xor(mt, 32, 64));
    float mn = fmaxf(mr, mt);
    float psum = 0.f;
    #pragma unroll
    for (int f = 0; f < 4; ++f)
        #pragma unroll
        for (int j = 0; j < 4; ++j) {
            float e = __expf(p[f][j] - mn);
            p[f][j] = e;
            psum += e;
        }
    psum += __shfl_xor(psum, 16, 64);
    psum += __shfl_xor(psum, 32, 64);
    float fc = __expf(mr - mn);
    mr = mn;
    lsum = lsum * fc + psum;
    #pragma unroll
    for (int dt = 0; dt < 4; ++dt)
        #pragma unroll
        for (int j = 0; j < 4; ++j) o[dt][j] *= fc;

    unsigned pk[4][2];
    #pragma unroll
    for (int f = 0; f < 4; ++f)
        #pragma unroll
        for (int pp = 0; pp < 2; ++pp)
            pk[f][pp] = ((unsigned)(unsigned short)f2bf(p[f][2 * pp + 1]) << 16)
                      |  (unsigned)(unsigned short)f2bf(p[f][2 * pp]);

    const int bsel = (lane >> 4) & 1, asel = (lane >> 5) & 1;
    #pragma unroll
    for (int c = 0; c < 2; ++c) {
        union { s16x8 v; int u[4]; } pb;
        #pragma unroll
        for (int w = 0; w < 4; ++w) {
            int src = q15 + 16 * (2 * bsel + (w >> 1));
            int lo = __shfl((int)pk[2 * c][w & 1], src, 64);
            int hi = __shfl((int)pk[2 * c + 1][w & 1], src, 64);
            pb.u[w] = asel ? hi : lo;
        }
        #pragma unroll
        for (int dt = 0; dt < 4; ++dt) {
            s16x8 vf = *(const s16x8*)((const char*)Vs + (16 * dt + q15) * 128 + ((c * 64 + g * 16) ^ sw));
            o[dt] = __builtin_amdgcn_mfma_f32_16x16x32_bf16(vf, pb.v, o[dt], 0, 0, 0);
        }
    }
    __syncthreads();
}

__device__ inline void stage_q64_swz(const short* __restrict__ qglob, int qld, short* Qs)
{
    int t = threadIdx.x;
    int row = t >> 2, c0 = (t & 3) * 16;
    int rsw = (row & 7) << 4;
    const short* src = qglob + (size_t)row * qld + c0;
    s16x8 a0 = ((const s16x8*)src)[0];
    s16x8 a1 = ((const s16x8*)src)[1];
    char* dst = (char*)Qs + row * 128;
    *(s16x8*)(dst + ((c0 * 2)      ^ rsw)) = a0;
    *(s16x8*)(dst + ((c0 * 2 + 16) ^ rsw)) = a1;
}

// ---------------------------------------------------------------- middle blocks
__global__ __launch_bounds__(256) void attn_middle_mfma(
    const short* __restrict__ qkv, const short* __restrict__ vT,
    const float* __restrict__ neg, const int* __restrict__ rand_attn, short* __restrict__ ctx)
{
    __shared__ short Qs[64 * 64];
    __shared__ short Ks[64 * 64];
    __shared__ short Vs[64 * 64];
    __shared__ float kmask[64];

    const int j = blockIdx.x, h = blockIdx.y, b = blockIdx.z;
    const int n = j + 1;
    const int t = threadIdx.x;
    const int lane = t & 63, wave = t >> 6;
    const int q15 = lane & 15, g = lane >> 4;
    const int sw = (lane & 7) << 4;

    stage_q64_swz(qkv + (size_t)(b * SEQ + n * 64) * QKVLD + h * HDIM, QKVLD, Qs);
    __syncthreads();

    s16x8 qfrag[2];
    {
        int qrow = wave * 16 + q15;
        #pragma unroll
        for (int ch = 0; ch < 2; ++ch)
            qfrag[ch] = *(const s16x8*)((const char*)Qs + qrow * 128 + ((ch * 64 + g * 16) ^ sw));
    }

    int kbl[8];
    kbl[0] = n - 1; kbl[1] = n; kbl[2] = n + 1; kbl[3] = 0; kbl[4] = NBLK - 1;
    {
        const int* ra = rand_attn + ((size_t)h * NMID + j) * NRAND;
        kbl[5] = ra[0]; kbl[6] = ra[1]; kbl[7] = ra[2];
    }

    f32x4 o[4];
    #pragma unroll
    for (int dt = 0; dt < 4; ++dt) o[dt] = f32x4{0.f, 0.f, 0.f, 0.f};
    float mr = -1e30f, lsum = 0.f;

    const short* kbase  = qkv + DIM + (size_t)b * SEQ * QKVLD + h * HDIM;
    const short* vtbase = vT + (size_t)(b * NHEAD + h) * HDIM * SEQ;
    const float* negb   = neg + (size_t)b * SEQ;

    #pragma unroll 1
    for (int ib = 0; ib < 8; ++ib) {
        int kbn = kbl[ib];
        attn_tile_mfma(kbase + (size_t)kbn * 64 * QKVLD, vtbase + kbn * 64,
                       negb + kbn * 64, QKVLD, Ks, Vs, kmask, qfrag, o, mr, lsum);
    }

    float inv = 1.f / lsum;
    short* obase = ctx + (size_t)(b * SEQ + n * 64 + wave * 16 + q15) * DIM + h * HDIM;
    #pragma unroll
    for (int dt = 0; dt < 4; ++dt) {
        s16x4 ov;
        #pragma unroll
        for (int jj = 0; jj < 4; ++jj) ov[jj] = f2bf(o[dt][jj] * inv);
        *(s16x4*)(obase + dt * 16 + g * 4) = ov;
    }
}

// ---------------------------------------------------------------- global blocks, split-K
__global__ __launch_bounds__(256) void attn_global_mfma(
    const short* __restrict__ qkv, const short* __restrict__ vT,
    const float* __restrict__ neg, float* __restrict__ part)
{
    __shared__ short Qs[64 * 64];
    __shared__ short Ks[64 * 64];
    __shared__ short Vs[64 * 64];
    __shared__ float kmask[64];

    const int qb = blockIdx.x >> 3, ks = blockIdx.x & 7;
    const int h = blockIdx.y, b = blockIdx.z;
    const int tok0 = qb ? (SEQ - 64) : 0;
    const int t = threadIdx.x;
    const int lane = t & 63, wave = t >> 6;
    const int q15 = lane & 15, g = lane >> 4;
    const int sw = (lane & 7) << 4;

    stage_q64_swz(qkv + (size_t)(b * SEQ + tok0) * QKVLD + h * HDIM, QKVLD, Qs);
    __syncthreads();

    s16x8 qfrag[2];
    {
        int qrow = wave * 16 + q15;
        #pragma unroll
        for (int ch = 0; ch < 2; ++ch)
            qfrag[ch] = *(const s16x8*)((const char*)Qs + qrow * 128 + ((ch * 64 + g * 16) ^ sw));
    }

    f32x4 o[4];
    #pragma unroll
    for (int dt = 0; dt < 4; ++dt) o[dt] = f32x4{0.f, 0.f, 0.f, 0.f};
    float mr = -1e30f, lsum = 0.f;

    const short* kbase  = qkv + DIM + (size_t)b * SEQ * QKVLD + h * HDIM;
    const short* vtbase = vT + (size_t)(b * NHEAD + h) * HDIM * SEQ;
    const float* negb   = neg + (size_t)b * SEQ;

    #pragma unroll 1
    for (int ib = 0; ib < 8; ++ib) {
        int kbn = ks * 8 + ib;
        attn_tile_mfma(kbase + (size_t)kbn * 64 * QKVLD, vtbase + kbn * 64,
                       negb + kbn * 64, QKVLD, Ks, Vs, kmask, qfrag, o, mr, lsum);
    }

    float* pbase = part + ((size_t)(((b * NHEAD + h) * 2 + qb) * KSPL + ks)) * 4224;
    int qrow = wave * 16 + q15;
    #pragma unroll
    for (int dt = 0; dt < 4; ++dt)
        *(f32x4*)(pbase + qrow * 64 + dt * 16 + g * 4) = o[dt];
    if (g == 0) { pbase[4096 + qrow] = mr; pbase[4160 + qrow] = lsum; }
}

// ---------------------------------------------------------------- merge global partials
__global__ __launch_bounds__(256) void attn_greduce(
    const float* __restrict__ part, short* __restrict__ ctx)
{
    const int qb = blockIdx.x, h = blockIdx.y, b = blockIdx.z;
    const int tok0 = qb ? (SEQ - 64) : 0;
    const int t = threadIdx.x;
    const int qq = t >> 2, d0 = (t & 3) * 16;
    const float* base = part + ((size_t)(((b * NHEAD + h) * 2 + qb) * KSPL)) * 4224;

    float m = -1e30f;
    #pragma unroll 1
    for (int s = 0; s < KSPL; ++s)
        m = fmaxf(m, base[(size_t)s * 4224 + 4096 + qq]);
    float L = 0.f;
    float acc[16];
    #pragma unroll
    for (int i = 0; i < 16; ++i) acc[i] = 0.f;
    #pragma unroll 1
    for (int s = 0; s < KSPL; ++s) {
        const float* bp = base + (size_t)s * 4224;
        float w = __expf(bp[4096 + qq] - m);
        L += w * bp[4160 + qq];
        const float4* row = (const float4*)(bp + qq * 64 + d0);
        #pragma unroll
        for (int v4 = 0; v4 < 4; ++v4) {
            float4 val = row[v4];
            acc[v4 * 4 + 0] = fmaf(w, val.x, acc[v4 * 4 + 0]);
            acc[v4 * 4 + 1] = fmaf(w, val.y, acc[v4 * 4 + 1]);
            acc[v4 * 4 + 2] = fmaf(w, val.z, acc[v4 * 4 + 2]);
            acc[v4 * 4 + 3] = fmaf(w, val.w, acc[v4 * 4 + 3]);
        }
    }
    float inv = 1.f / L;
    short* dst = ctx + (size_t)(b * SEQ + tok0 + qq) * DIM + h * HDIM + d0;
    s16x8 o0, o1;
    #pragma unroll
    for (int i = 0; i < 8; ++i) { o0[i] = f2bf(acc[i] * inv); o1[i] = f2bf(acc[8 + i] * inv); }
    ((s16x8*)dst)[0] = o0;
    ((s16x8*)dst)[1] = o1;
}

// ---------------------------------------------------------------- column mean, stage 1
__global__ __launch_bounds__(256) void colsum1_kernel(
    const float* __restrict__ xln, float* __restrict__ partial)
{
    const int ch = blockIdx.x, b = blockIdx.y, t = threadIdx.x;
    const float* base = xln + ((size_t)b * SEQ + ch * 32) * DIM + t * 4;
    float4 acc = {0.f, 0.f, 0.f, 0.f};
    #pragma unroll 4
    for (int r = 0; r < 32; ++r) {
        float4 v = *(const float4*)(base + (size_t)r * DIM);
        acc.x += v.x; acc.y += v.y; acc.z += v.z; acc.w += v.w;
    }
    *(float4*)(partial + ((size_t)(b * 128 + ch)) * DIM + t * 4) = acc;
}

// ---------------------------------------------------------------- column mean, stage 2
__global__ __launch_bounds__(256) void colsum2_kernel(
    const float* __restrict__ partial, float* __restrict__ feats)
{
    const int b = blockIdx.x, t = threadIdx.x;
    float4 acc = {0.f, 0.f, 0.f, 0.f};
    #pragma unroll 1
    for (int ch = 0; ch < 128; ++ch) {
        float4 v = *(const float4*)(partial + ((size_t)(b * 128 + ch)) * DIM + t * 4);
        acc.x += v.x; acc.y += v.y; acc.z += v.z; acc.w += v.w;
    }
    const float is = 1.f / SEQ;
    float4 o = { acc.x * is, acc.y * is, acc.z * is, acc.w * is };
    *(float4*)(feats + (size_t)b * DIM + t * 4) = o;
}

// ---------------------------------------------------------------- normalize + project
__global__ __launch_bounds__(256) void head_kernel(
    const float* __restrict__ feats, const float* __restrict__ projW,
    const float* __restrict__ projb, float* __restrict__ out)
{
    __shared__ float f[DIM];
    __shared__ float slots[4];
    int b = blockIdx.x, t = threadIdx.x;
    float ss = 0.f;
    for (int i = t; i < DIM; i += 256) {
        float vv = feats[b * DIM + i];
        f[i] = vv;
        ss += vv * vv;
    }
    #pragma unroll
    for (int o = 32; o > 0; o >>= 1) ss += __shfl_xor(ss, o, 64);
    if ((t & 63) == 0) slots[t >> 6] = ss;
    __syncthreads();
    float nrm = sqrtf(slots[0] + slots[1] + slots[2] + slots[3]);
    float inv = 1.f / fmaxf(nrm, 1e-12f);
    for (int o = t; o < 512; o += 256) {
        float acc = 0.f;
        for (int d = 0; d < DIM; ++d)
            acc = fmaf(f[d], projW[(size_t)d * 512 + o], acc);
        out[b * 512 + o] = acc * inv + projb[o];
    }
}

// ---------------------------------------------------------------- launch
extern "C" void kernel_launch(void* const* d_in, const int* in_sizes, int n_in,
                              void* d_out, int out_size, void* d_ws, size_t ws_size,
                              hipStream_t stream)
{
    (void)in_sizes; (void)n_in; (void)out_size; (void)ws_size;
    const int*   ids   = (const int*)d_in[0];
    const int*   amask = (const int*)d_in[1];
    const int*   rnd   = (const int*)d_in[2];
    const float* emb   = (const float*)d_in[3];
    const float* Wq    = (const float*)d_in[4];
    const float* bq    = (const float*)d_in[5];
    const float* Wk    = (const float*)d_in[6];
    const float* bk    = (const float*)d_in[7];
    const float* Wv    = (const float*)d_in[8];
    const float* bv    = (const float*)d_in[9];
    const float* Wo    = (const float*)d_in[10];
    const float* bo    = (const float*)d_in[11];
    const float* ln1g  = (const float*)d_in[12];
    const float* ln1b  = (const float*)d_in[13];
    const float* W1    = (const float*)d_in[14];
    const float* b1    = (const float*)d_in[15];
    const float* W2    = (const float*)d_in[16];
    const float* b2    = (const float*)d_in[17];
    const float* ln2g  = (const float*)d_in[18];
    const float* ln2b  = (const float*)d_in[19];
    const float* lnfg  = (const float*)d_in[20];
    const float* lnfb  = (const float*)d_in[21];
    const float* projW = (const float*)d_in[22];
    const float* projb = (const float*)d_in[23];
    float* out = (float*)d_out;

    char* ws = (char*)d_ws;
    size_t off = 0;
    float* x    = (float*)(ws + off); off += (size_t)ROWS * DIM * 4;
    float* xn_f = (float*)(ws + off);
    short* xn_b = (short*)(ws + off); off += (size_t)ROWS * DIM * 4;
    short* qkv  = (short*)(ws + off); off += (size_t)ROWS * QKVLD * 2;   // 48 MB
    short* vT   = (short*)(ws + off); off += (size_t)ROWS * DIM * 2;     // 16 MB
    short* ctxb = (short*)(ws + off); off += (size_t)ROWS * DIM * 2;
    short* ffb  = (short*)(ws + off); off += (size_t)ROWS * FFDIM * 2;
    short* wt4  = (short*)(ws + off); off += (size_t)NLAYER * WLAYER * 2; // 96 MB
    float* neg  = (float*)(ws + off); off += (size_t)ROWS * 4;
    float* bias3= (float*)(ws + off); off += (size_t)NLAYER * QKVLD * 4;
    float* feats= (float*)(ws + off); off += (size_t)BATCH * DIM * 4;
    float* part = (float*)(ws + off); off += (size_t)BATCH * NHEAD * 2 * KSPL * 4224 * 4;
    float* cpart= (float*)(ws + off); off += (size_t)BATCH * 128 * DIM * 4;
    // FF2 split-K fp32 partials (2 x 32 MB) alias qkv+vT (dead by FF2 time)
    float* ff2p = (float*)qkv;

    embed_kernel<<<ROWS, 256, 0, stream>>>(ids, emb, x);
    neg_kernel<<<(ROWS + 255) / 256, 256, 0, stream>>>(amask, neg);

    // batched weight conversions: 3 dispatches + 1 biaspack
    wconv4_kernel<<<dim3(DIM/32, DIM/32, NLAYER*4), 256, 0, stream>>>(Wq, Wk, Wv, Wo, wt4);
    wconvff_kernel<<<dim3(DIM/32, FFDIM/32, NLAYER), 256, 0, stream>>>(W1, wt4, DIM, FFDIM, (size_t)4*1024*1024);
    wconvff_kernel<<<dim3(FFDIM/32, DIM/32, NLAYER), 256, 0, stream>>>(W2, wt4, FFDIM, DIM, (size_t)8*1024*1024);
    biaspack_kernel<<<dim3(QKVLD/256, NLAYER), 256, 0, stream>>>(bq, bk, bv, bias3);

    for (int l = 0; l < NLAYER; ++l) {
        short* wq3 = wt4 + (size_t)l * WLAYER;
        short* wo  = wq3 + 3 * 1024 * 1024;
        short* w1t = wo  + 1024 * 1024;
        short* w2t = w1t + 4 * 1024 * 1024;

        if (l == 0)
            ln_kernel<1><<<ROWS, 256, 0, stream>>>(x, ln1g, ln1b, xn_b);

        gemm256_kernel<0><<<dim3(ROWS/256, QKVLD/256), 512, 0, stream>>>(xn_b, wq3, bias3 + (size_t)l*QKVLD, qkv, ROWS, QKVLD, DIM, DIM);

        vtrans_kernel<<<dim3(SEQ/64, NHEAD, BATCH), 256, 0, stream>>>(qkv, vT);

        attn_global_mfma<<<dim3(2 * KSPL, NHEAD, BATCH), 256, 0, stream>>>(qkv, vT, neg, part);
        attn_middle_mfma<<<dim3(NMID, NHEAD, BATCH), 256, 0, stream>>>(qkv, vT, neg, rnd, ctxb);
        attn_greduce<<<dim3(2, NHEAD, BATCH), 256, 0, stream>>>(part, ctxb);

        gemm_kernel<2><<<dim3(ROWS/128, DIM/128), 256, 0, stream>>>(ctxb, wo, bo + l*DIM, x, x, ROWS, DIM, DIM, DIM);

        ln_kernel<1><<<ROWS, 256, 0, stream>>>(x, ln2g + l * DIM, ln2b + l * DIM, xn_b);

        gemm256_kernel<1><<<dim3(ROWS/256, FFDIM/256), 512, 0, stream>>>(xn_b, w1t, b1 + l*FFDIM, ffb, ROWS, FFDIM, DIM, DIM);
        gemm256_kernel<3><<<dim3(ROWS/256, DIM/256, 2), 512, 0, stream>>>(ffb, w2t, nullptr, ff2p, ROWS, DIM, FFDIM, FFDIM/2);

        if (l < NLAYER - 1)
            kred_ln_kernel<0><<<ROWS, 256, 0, stream>>>(ff2p, b2 + l*DIM, ln1g + (l+1)*DIM, ln1b + (l+1)*DIM, x, xn_b);
        else
            kred_ln_kernel<1><<<ROWS, 256, 0, stream>>>(ff2p, b2 + l*DIM, lnfg, lnfb, x, xn_f);
    }

    colsum1_kernel<<<dim3(SEQ/32, BATCH), 256, 0, stream>>>(xn_f, cpart);
    colsum2_kernel<<<BATCH, 256, 0, stream>>>(cpart, feats);
    head_kernel<<<BATCH, 256, 0, stream>>>(feats, projW, projb, out);
}

// Round 13
// 1772.649 us; speedup vs baseline: 1.1053x; 1.0754x over previous
//
#include <hip/hip_runtime.h>
#include <hip/hip_bf16.h>
#include <cstdint>
#include <cstddef>

#define BATCH 2
#define SEQ   4096
#define DIM   1024
#define NHEAD 16
#define HDIM  64
#define NBLK  64
#define NMID  62
#define NRAND 3
#define NLAYER 4
#define FFDIM 4096
#define ROWS  (BATCH*SEQ)   // 8192
#define KSPL  8             // key splits for global attention
#define QKVLD (3*DIM)       // fused qkv row stride

using f32x4 = __attribute__((ext_vector_type(4))) float;
using s16x8 = __attribute__((ext_vector_type(8))) short;
using s16x4 = __attribute__((ext_vector_type(4))) short;

__device__ inline float bf2f(short s) {
    unsigned u = ((unsigned)(unsigned short)s) << 16;
    union { unsigned u; float f; } cv; cv.u = u; return cv.f;
}
__device__ inline short f2bf(float f) {
    union { float f; unsigned u; } cv; cv.f = f;
    unsigned u = cv.u;
    unsigned r = (u + 0x7fffu + ((u >> 16) & 1u)) >> 16;  // RNE
    return (short)r;
}
// exact-formula tanh-gelu, but tanh via hardware __expf (~1e-6 rel err, << bf16 ulp)
__device__ inline float gelu_f(float x) {
    float u = 0.7978845608028654f * (x + 0.044715f * x * x * x);
    float a = fabsf(u);
    float th = 1.f - 2.f / (1.f + __expf(2.f * a));
    th = copysignf(th, u);
    return 0.5f * x * (1.f + th);
}

// async global->LDS, 16B per lane; LDS dest is wave-uniform base + lane*16B
__device__ inline void gload16(const short* g, short* l) {
    __builtin_amdgcn_global_load_lds(
        (const __attribute__((address_space(1))) void*)g,
        (__attribute__((address_space(3))) void*)l,
        16, 0, 0);
}

// ---------------------------------------------------------------- embedding
__global__ __launch_bounds__(256) void embed_kernel(
    const int* __restrict__ ids, const float* __restrict__ emb, float* __restrict__ x)
{
    int row = blockIdx.x;
    int id  = ids[row];
    ((float4*)x)[(size_t)row * 256 + threadIdx.x] =
        ((const float4*)emb)[(size_t)id * 256 + threadIdx.x];
}

// ---------------------------------------------------------------- neg mask
__global__ __launch_bounds__(256) void neg_kernel(
    const int* __restrict__ mask, float* __restrict__ neg)
{
    int i = blockIdx.x * 256 + threadIdx.x;
    if (i < ROWS) neg[i] = (1.f - (float)mask[i]) * -1e9f;
}

// ---------------------------------------------------------------- bias pack (qkv)
__global__ __launch_bounds__(256) void biaspack_kernel(
    const float* __restrict__ bq, const float* __restrict__ bk,
    const float* __restrict__ bv, float* __restrict__ b3)
{
    int i = blockIdx.x * 256 + threadIdx.x;   // 0..3071
    float v = (i < DIM) ? bq[i] : (i < 2 * DIM) ? bk[i - DIM] : bv[i - 2 * DIM];
    b3[i] = v;
}

// ---------------------------------------------------------------- layernorm (row=1024)
template<int OUTBF>
__global__ __launch_bounds__(256) void ln_kernel(
    const float* __restrict__ x, const float* __restrict__ g,
    const float* __restrict__ bia, void* __restrict__ out)
{
    __shared__ float s1[4], s2[4];
    int row = blockIdx.x, t = threadIdx.x;
    const float* xr = x + (size_t)row * DIM;
    float4 v = ((const float4*)xr)[t];
    float s = v.x + v.y + v.z + v.w;
    #pragma unroll
    for (int o = 32; o > 0; o >>= 1) s += __shfl_xor(s, o, 64);
    if ((t & 63) == 0) s1[t >> 6] = s;
    __syncthreads();
    float mu = (s1[0] + s1[1] + s1[2] + s1[3]) * (1.f / DIM);
    float dx = v.x - mu, dy = v.y - mu, dz = v.z - mu, dw = v.w - mu;
    float q = dx*dx + dy*dy + dz*dz + dw*dw;
    #pragma unroll
    for (int o = 32; o > 0; o >>= 1) q += __shfl_xor(q, o, 64);
    if ((t & 63) == 0) s2[t >> 6] = q;
    __syncthreads();
    float var = (s2[0] + s2[1] + s2[2] + s2[3]) * (1.f / DIM);
    float rs  = rsqrtf(var + 1e-5f);
    float4 gg = ((const float4*)g)[t];
    float4 bb = ((const float4*)bia)[t];
    float o0 = dx * rs * gg.x + bb.x;
    float o1 = dy * rs * gg.y + bb.y;
    float o2 = dz * rs * gg.z + bb.z;
    float o3 = dw * rs * gg.w + bb.w;
    if (OUTBF) {
        s16x4 ov = { f2bf(o0), f2bf(o1), f2bf(o2), f2bf(o3) };
        ((s16x4*)out)[(size_t)row * (DIM/4) + t] = ov;
    } else {
        float4 ov = { o0, o1, o2, o3 };
        ((float4*)out)[(size_t)row * (DIM/4) + t] = ov;
    }
}

// ---------------------------------------------------------------- weight transpose + bf16
__global__ __launch_bounds__(256) void wconv_kernel(
    const float* __restrict__ W, short* __restrict__ Wt, int K, int N)
{
    __shared__ float tile[32][33];
    int k0 = blockIdx.x * 32, n0 = blockIdx.y * 32;
    int t = threadIdx.x;
    int r = t >> 3, c = (t & 7) * 4;
    float4 v = *(const float4*)(W + (size_t)(k0 + r) * N + n0 + c);
    tile[r][c+0] = v.x; tile[r][c+1] = v.y; tile[r][c+2] = v.z; tile[r][c+3] = v.w;
    __syncthreads();
    s16x4 ov;
    #pragma unroll
    for (int jj = 0; jj < 4; ++jj) ov[jj] = f2bf(tile[c + jj][r]);
    *(s16x4*)(Wt + (size_t)(n0 + r) * K + k0 + c) = ov;
}

// ---------------------------------------------------------------- V transpose (per head)
__global__ __launch_bounds__(256) void vtrans_kernel(
    const short* __restrict__ qkv, short* __restrict__ vT)
{
    __shared__ short tile[64][66];
    const int sb = blockIdx.x, h = blockIdx.y, b = blockIdx.z;
    const int t = threadIdx.x;
    {
        int row = t >> 2, c0 = (t & 3) * 16;
        const short* src = qkv + 2 * DIM + (size_t)(b * SEQ + sb * 64 + row) * QKVLD + h * HDIM + c0;
        s16x8 a0 = ((const s16x8*)src)[0];
        s16x8 a1 = ((const s16x8*)src)[1];
        #pragma unroll
        for (int i = 0; i < 8; ++i) { tile[row][c0 + i] = a0[i]; tile[row][c0 + 8 + i] = a1[i]; }
    }
    __syncthreads();
    {
        int d = t >> 2, k0 = (t & 3) * 16;
        s16x8 o0, o1;
        #pragma unroll
        for (int i = 0; i < 8; ++i) { o0[i] = tile[k0 + i][d]; o1[i] = tile[k0 + 8 + i][d]; }
        short* dst = vT + (size_t)((b * NHEAD + h) * HDIM + d) * SEQ + sb * 64 + k0;
        ((s16x8*)dst)[0] = o0;
        ((s16x8*)dst)[1] = o1;
    }
}

// ---------------------------------------------------------------- GEMM 256x256, 8-wave, dbuf
// C[M,N] = A[M,K](bf16) * Bt[N,K]^T(bf16) + bias
// EPI 0: bf16 ; 1: bf16+gelu ; 3: fp32 raw partial (split-K via blockIdx.z)
// LDS 2x64KB double buffer; STAGE(next) issued BEFORE 64-MFMA compute so the
// tile-end __syncthreads' implicit vmcnt(0) finds loads landed.
// Linear LDS dest + pre-swizzled global source; reads apply matching XOR (rule 21).
template<int EPI>
__global__ __launch_bounds__(512) void gemm256_kernel(
    const short* __restrict__ A, const short* __restrict__ Bt,
    const float* __restrict__ bias, const float* __restrict__ resid,
    void* __restrict__ Cout, int M, int N, int K, int klen)
{
    __shared__ short As[2][256 * 64];   // 2 x 32KB
    __shared__ short Bs[2][256 * 64];   // 2 x 32KB  -> 128KB total
    const int t = threadIdx.x;
    const int m0 = blockIdx.x * 256, n0 = blockIdx.y * 256;
    const int lane = t & 63, wave = t >> 6;
    const int wm = wave >> 2, wn = wave & 3;         // 2 x 4 wave grid
    const int lrow = lane >> 3;                      // 0..7 in 8-row chunk
    const int lksw = ((lane & 7) ^ lrow) * 8;        // pre-swizzled source k-offset

    f32x4 acc[8][4];
    #pragma unroll
    for (int m = 0; m < 8; ++m)
        #pragma unroll
        for (int n = 0; n < 4; ++n)
            acc[m][n] = f32x4{0.f, 0.f, 0.f, 0.f};

    auto STAGE = [&](int side, int kt) {
        #pragma unroll
        for (int c = 0; c < 4; ++c) {
            int chunk = wave + c * 8;                // 0..31 (8 rows each)
            int row = chunk * 8 + lrow;              // 0..255
            gload16(A  + (size_t)(m0 + row) * K + kt + lksw, &As[side][chunk * 512]);
            gload16(Bt + (size_t)(n0 + row) * K + kt + lksw, &Bs[side][chunk * 512]);
        }
    };

    const int k0 = blockIdx.z * klen, kend = k0 + klen;
    STAGE(0, k0);
    __syncthreads();

    int cur = 0;
    for (int kt = k0; kt < kend; kt += 64) {
        if (kt + 64 < kend) STAGE(cur ^ 1, kt + 64);   // prefetch (in flight across compute)
        const short* Ac = As[cur];
        const short* Bc = Bs[cur];
        #pragma unroll
        for (int kk = 0; kk < 2; ++kk) {
            const int cb = kk * 64 + (lane >> 4) * 16;
            s16x8 bfr[4];
            #pragma unroll
            for (int n = 0; n < 4; ++n) {
                int rB = wn * 64 + n * 16 + (lane & 15);
                bfr[n] = *(const s16x8*)((const char*)Bc + rB * 128 + (cb ^ ((rB & 7) << 4)));
            }
            #pragma unroll
            for (int mq = 0; mq < 4; ++mq) {
                s16x8 af[2];
                #pragma unroll
                for (int i = 0; i < 2; ++i) {
                    int rA = wm * 128 + mq * 32 + i * 16 + (lane & 15);
                    af[i] = *(const s16x8*)((const char*)Ac + rA * 128 + (cb ^ ((rA & 7) << 4)));
                }
                #pragma unroll
                for (int i = 0; i < 2; ++i)
                    #pragma unroll
                    for (int n = 0; n < 4; ++n)
                        acc[mq * 2 + i][n] = __builtin_amdgcn_mfma_f32_16x16x32_bf16(
                            af[i], bfr[n], acc[mq * 2 + i][n], 0, 0, 0);
            }
        }
        __syncthreads();   // drains prefetch (landed during 64 MFMA) + joins reads
        cur ^= 1;
    }

    const int rbase = m0 + wm * 128 + ((lane >> 4) << 2);
    const int cbase = n0 + wn * 64 + (lane & 15);
    #pragma unroll
    for (int m = 0; m < 8; ++m) {
        #pragma unroll
        for (int n = 0; n < 4; ++n) {
            #pragma unroll
            for (int j = 0; j < 4; ++j) {
                int row = rbase + m * 16 + j;
                int col = cbase + n * 16;
                size_t idx = (size_t)row * N + col;
                float val = acc[m][n][j];
                if (EPI == 3) {
                    ((float*)Cout)[(size_t)blockIdx.z * ((size_t)M * N) + idx] = val;
                } else {
                    val += bias[col];
                    if (EPI == 1) val = gelu_f(val);
                    ((short*)Cout)[idx] = f2bf(val);
                }
            }
        }
    }
    (void)resid;
}

// ---------------------------------------------------------------- GEMM 128x128 (O-proj)
// EPI 2: out fp32 + residual add
template<int EPI>
__global__ __launch_bounds__(256) void gemm_kernel(
    const short* __restrict__ A, const short* __restrict__ Bt,
    const float* __restrict__ bias, const float* __restrict__ resid,
    void* __restrict__ Cout, int M, int N, int K, int klen)
{
    __shared__ short As[128 * 64];
    __shared__ short Bs[128 * 64];
    const int t = threadIdx.x;
    const int m0 = blockIdx.x * 128, n0 = blockIdx.y * 128;
    const int lane = t & 63, wave = t >> 6;
    const int wr = (wave >> 1) * 64, wc = (wave & 1) * 64;
    const int lrow = lane >> 3;
    const int lksw = ((lane & 7) ^ lrow) * 8;

    f32x4 acc[4][4];
    #pragma unroll
    for (int m = 0; m < 4; ++m)
        #pragma unroll
        for (int n = 0; n < 4; ++n)
            acc[m][n] = f32x4{0.f, 0.f, 0.f, 0.f};

    const int k0 = blockIdx.z * klen;
    for (int kt = k0; kt < k0 + klen; kt += 64) {
        #pragma unroll
        for (int c = 0; c < 4; ++c) {
            int chunk = wave * 4 + c;
            int row = chunk * 8 + lrow;
            gload16(A  + (size_t)(m0 + row) * K + kt + lksw, As + chunk * 512);
            gload16(Bt + (size_t)(n0 + row) * K + kt + lksw, Bs + chunk * 512);
        }
        asm volatile("s_waitcnt vmcnt(0)" ::: "memory");
        __syncthreads();
        #pragma unroll
        for (int kk = 0; kk < 2; ++kk) {
            s16x8 af[4], bfr[4];
            int cb = kk * 64 + (lane >> 4) * 16;
            #pragma unroll
            for (int i = 0; i < 4; ++i) {
                int rA = wr + i * 16 + (lane & 15);
                af[i]  = *(const s16x8*)((const char*)As + rA * 128 + (cb ^ ((rA & 7) << 4)));
                int rB = wc + i * 16 + (lane & 15);
                bfr[i] = *(const s16x8*)((const char*)Bs + rB * 128 + (cb ^ ((rB & 7) << 4)));
            }
            #pragma unroll
            for (int m = 0; m < 4; ++m)
                #pragma unroll
                for (int n = 0; n < 4; ++n)
                    acc[m][n] = __builtin_amdgcn_mfma_f32_16x16x32_bf16(
                        af[m], bfr[n], acc[m][n], 0, 0, 0);
        }
        __syncthreads();
    }

    const int rbase = m0 + wr + ((lane >> 4) << 2);
    const int cbase = n0 + wc + (lane & 15);
    #pragma unroll
    for (int m = 0; m < 4; ++m) {
        #pragma unroll
        for (int n = 0; n < 4; ++n) {
            #pragma unroll
            for (int j = 0; j < 4; ++j) {
                int row = rbase + m * 16 + j;
                int col = cbase + n * 16;
                size_t idx = (size_t)row * N + col;
                float val = acc[m][n][j] + bias[col];
                if (EPI == 1) val = gelu_f(val);
                if (EPI == 2) ((float*)Cout)[idx] = val + resid[idx];
                else          ((short*)Cout)[idx] = f2bf(val);
            }
        }
    }
}

// ---------------------------------------------------------------- split-K reduce (FF2)
__global__ __launch_bounds__(256) void kred_kernel(
    const float* __restrict__ part, const float* __restrict__ bias, float* __restrict__ x)
{
    const size_t MN = (size_t)ROWS * DIM;
    size_t idx = (size_t)blockIdx.x * DIM + threadIdx.x * 4;
    float4 p0 = *(const float4*)(part + idx);
    float4 p1 = *(const float4*)(part + MN + idx);
    float4 bb = *(const float4*)(bias + threadIdx.x * 4);
    float4 xv = *(const float4*)(x + idx);
    float4 o = { xv.x + p0.x + p1.x + bb.x,
                 xv.y + p0.y + p1.y + bb.y,
                 xv.z + p0.z + p1.z + bb.z,
                 xv.w + p0.w + p1.w + bb.w };
    *(float4*)(x + idx) = o;
}

// ================================================================ MFMA attention
__device__ inline void attn_tile_mfma(
    const short* __restrict__ kglob, const short* __restrict__ vtglob,
    const float* __restrict__ negp, int kld,
    short* Ks, short* Vs, float* kmask,
    const s16x8* qfrag, f32x4* o, float& mr, float& lsum)
{
    const int t = threadIdx.x;
    const int lane = t & 63;
    const int q15 = lane & 15, g = lane >> 4;
    const int sw = (lane & 7) << 4;

    {   // stage K [k][d] and V^T [d][k], swizzled
        int row = t >> 2, c0 = (t & 3) * 16;
        int rsw = (row & 7) << 4;
        const short* ksrc = kglob + (size_t)row * kld + c0;
        s16x8 a0 = ((const s16x8*)ksrc)[0];
        s16x8 a1 = ((const s16x8*)ksrc)[1];
        char* kdst = (char*)Ks + row * 128;
        *(s16x8*)(kdst + ((c0 * 2)      ^ rsw)) = a0;
        *(s16x8*)(kdst + ((c0 * 2 + 16) ^ rsw)) = a1;
        const short* vsrc = vtglob + (size_t)row * SEQ + c0;
        s16x8 b0 = ((const s16x8*)vsrc)[0];
        s16x8 b1 = ((const s16x8*)vsrc)[1];
        char* vdst = (char*)Vs + row * 128;
        *(s16x8*)(vdst + ((c0 * 2)      ^ rsw)) = b0;
        *(s16x8*)(vdst + ((c0 * 2 + 16) ^ rsw)) = b1;
        if (t < 16) ((float4*)kmask)[t] = ((const float4*)negp)[t];
    }
    __syncthreads();

    f32x4 s[4];
    #pragma unroll
    for (int f = 0; f < 4; ++f) s[f] = f32x4{0.f, 0.f, 0.f, 0.f};
    #pragma unroll
    for (int ch = 0; ch < 2; ++ch) {
        #pragma unroll
        for (int f = 0; f < 4; ++f) {
            s16x8 kf = *(const s16x8*)((const char*)Ks + (16 * f + q15) * 128 + ((ch * 64 + g * 16) ^ sw));
            s[f] = __builtin_amdgcn_mfma_f32_16x16x32_bf16(kf, qfrag[ch], s[f], 0, 0, 0);
        }
    }

    float p[4][4];
    float mt = -1e30f;
    #pragma unroll
    for (int f = 0; f < 4; ++f) {
        float4 km = ((const float4*)kmask)[f * 4 + g];
        #pragma unroll
        for (int j = 0; j < 4; ++j) {
            float val = s[f][j] * 0.125f + ((const float*)&km)[j];
            p[f][j] = val;
            mt = fmaxf(mt, val);
        }
    }
    mt = fmaxf(mt, __shfl_xor(mt, 16, 64));
    mt = fmaxf(mt, __shfl_xor(mt, 32, 64));
    float mn = fmaxf(mr, mt);
    float psum = 0.f;
    #pragma unroll
    for (int f = 0; f < 4; ++f)
        #pragma unroll
        for (int j = 0; j < 4; ++j) {
            float e = __expf(p[f][j] - mn);
            p[f][j] = e;
            psum += e;
        }
    psum += __shfl_xor(psum, 16, 64);
    psum += __shfl_xor(psum, 32, 64);
    float fc = __expf(mr - mn);
    mr = mn;
    lsum = lsum * fc + psum;
    #pragma unroll
    for (int dt = 0; dt < 4; ++dt)
        #pragma unroll
        for (int j = 0; j < 4; ++j) o[dt][j] *= fc;

    unsigned pk[4][2];
    #pragma unroll
    for (int f = 0; f < 4; ++f)
        #pragma unroll
        for (int pp = 0; pp < 2; ++pp)
            pk[f][pp] = ((unsigned)(unsigned short)f2bf(p[f][2 * pp + 1]) << 16)
                      |  (unsigned)(unsigned short)f2bf(p[f][2 * pp]);

    const int bsel = (lane >> 4) & 1, asel = (lane >> 5) & 1;
    #pragma unroll
    for (int c = 0; c < 2; ++c) {
        union { s16x8 v; int u[4]; } pb;
        #pragma unroll
        for (int w = 0; w < 4; ++w) {
            int src = q15 + 16 * (2 * bsel + (w >> 1));
            int lo = __shfl((int)pk[2 * c][w & 1], src, 64);
            int hi = __shfl((int)pk[2 * c + 1][w & 1], src, 64);
            pb.u[w] = asel ? hi : lo;
        }
        #pragma unroll
        for (int dt = 0; dt < 4; ++dt) {
            s16x8 vf = *(const s16x8*)((const char*)Vs + (16 * dt + q15) * 128 + ((c * 64 + g * 16) ^ sw));
            o[dt] = __builtin_amdgcn_mfma_f32_16x16x32_bf16(vf, pb.v, o[dt], 0, 0, 0);
        }
    }
    __syncthreads();
}

__device__ inline void stage_q64_swz(const short* __restrict__ qglob, int qld, short* Qs)
{
    int t = threadIdx.x;
    int row = t >> 2, c0 = (t & 3) * 16;
    int rsw = (row & 7) << 4;
    const short* src = qglob + (size_t)row * qld + c0;
    s16x8 a0 = ((const s16x8*)src)[0];
    s16x8 a1 = ((const s16x8*)src)[1];
    char* dst = (char*)Qs + row * 128;
    *(s16x8*)(dst + ((c0 * 2)      ^ rsw)) = a0;
    *(s16x8*)(dst + ((c0 * 2 + 16) ^ rsw)) = a1;
}

// ---------------------------------------------------------------- middle blocks
__global__ __launch_bounds__(256) void attn_middle_mfma(
    const short* __restrict__ qkv, const short* __restrict__ vT,
    const float* __restrict__ neg, const int* __restrict__ rand_attn, short* __restrict__ ctx)
{
    __shared__ short Qs[64 * 64];
    __shared__ short Ks[64 * 64];
    __shared__ short Vs[64 * 64];
    __shared__ float kmask[64];

    const int j = blockIdx.x, h = blockIdx.y, b = blockIdx.z;
    const int n = j + 1;
    const int t = threadIdx.x;
    const int lane = t & 63, wave = t >> 6;
    const int q15 = lane & 15, g = lane >> 4;
    const int sw = (lane & 7) << 4;

    stage_q64_swz(qkv + (size_t)(b * SEQ + n * 64) * QKVLD + h * HDIM, QKVLD, Qs);
    __syncthreads();

    s16x8 qfrag[2];
    {
        int qrow = wave * 16 + q15;
        #pragma unroll
        for (int ch = 0; ch < 2; ++ch)
            qfrag[ch] = *(const s16x8*)((const char*)Qs + qrow * 128 + ((ch * 64 + g * 16) ^ sw));
    }

    int kbl[8];
    kbl[0] = n - 1; kbl[1] = n; kbl[2] = n + 1; kbl[3] = 0; kbl[4] = NBLK - 1;
    {
        const int* ra = rand_attn + ((size_t)h * NMID + j) * NRAND;
        kbl[5] = ra[0]; kbl[6] = ra[1]; kbl[7] = ra[2];
    }

    f32x4 o[4];
    #pragma unroll
    for (int dt = 0; dt < 4; ++dt) o[dt] = f32x4{0.f, 0.f, 0.f, 0.f};
    float mr = -1e30f, lsum = 0.f;

    const short* kbase  = qkv + DIM + (size_t)b * SEQ * QKVLD + h * HDIM;
    const short* vtbase = vT + (size_t)(b * NHEAD + h) * HDIM * SEQ;
    const float* negb   = neg + (size_t)b * SEQ;

    #pragma unroll 1
    for (int ib = 0; ib < 8; ++ib) {
        int kbn = kbl[ib];
        attn_tile_mfma(kbase + (size_t)kbn * 64 * QKVLD, vtbase + kbn * 64,
                       negb + kbn * 64, QKVLD, Ks, Vs, kmask, qfrag, o, mr, lsum);
    }

    float inv = 1.f / lsum;
    short* obase = ctx + (size_t)(b * SEQ + n * 64 + wave * 16 + q15) * DIM + h * HDIM;
    #pragma unroll
    for (int dt = 0; dt < 4; ++dt) {
        s16x4 ov;
        #pragma unroll
        for (int jj = 0; jj < 4; ++jj) ov[jj] = f2bf(o[dt][jj] * inv);
        *(s16x4*)(obase + dt * 16 + g * 4) = ov;
    }
}

// ---------------------------------------------------------------- global blocks, split-K
__global__ __launch_bounds__(256) void attn_global_mfma(
    const short* __restrict__ qkv, const short* __restrict__ vT,
    const float* __restrict__ neg, float* __restrict__ part)
{
    __shared__ short Qs[64 * 64];
    __shared__ short Ks[64 * 64];
    __shared__ short Vs[64 * 64];
    __shared__ float kmask[64];

    const int qb = blockIdx.x >> 3, ks = blockIdx.x & 7;
    const int h = blockIdx.y, b = blockIdx.z;
    const int tok0 = qb ? (SEQ - 64) : 0;
    const int t = threadIdx.x;
    const int lane = t & 63, wave = t >> 6;
    const int q15 = lane & 15, g = lane >> 4;
    const int sw = (lane & 7) << 4;

    stage_q64_swz(qkv + (size_t)(b * SEQ + tok0) * QKVLD + h * HDIM, QKVLD, Qs);
    __syncthreads();

    s16x8 qfrag[2];
    {
        int qrow = wave * 16 + q15;
        #pragma unroll
        for (int ch = 0; ch < 2; ++ch)
            qfrag[ch] = *(const s16x8*)((const char*)Qs + qrow * 128 + ((ch * 64 + g * 16) ^ sw));
    }

    f32x4 o[4];
    #pragma unroll
    for (int dt = 0; dt < 4; ++dt) o[dt] = f32x4{0.f, 0.f, 0.f, 0.f};
    float mr = -1e30f, lsum = 0.f;

    const short* kbase  = qkv + DIM + (size_t)b * SEQ * QKVLD + h * HDIM;
    const short* vtbase = vT + (size_t)(b * NHEAD + h) * HDIM * SEQ;
    const float* negb   = neg + (size_t)b * SEQ;

    #pragma unroll 1
    for (int ib = 0; ib < 8; ++ib) {
        int kbn = ks * 8 + ib;
        attn_tile_mfma(kbase + (size_t)kbn * 64 * QKVLD, vtbase + kbn * 64,
                       negb + kbn * 64, QKVLD, Ks, Vs, kmask, qfrag, o, mr, lsum);
    }

    float* pbase = part + ((size_t)(((b * NHEAD + h) * 2 + qb) * KSPL + ks)) * 4224;
    int qrow = wave * 16 + q15;
    #pragma unroll
    for (int dt = 0; dt < 4; ++dt)
        *(f32x4*)(pbase + qrow * 64 + dt * 16 + g * 4) = o[dt];
    if (g == 0) { pbase[4096 + qrow] = mr; pbase[4160 + qrow] = lsum; }
}

// ---------------------------------------------------------------- merge global partials
__global__ __launch_bounds__(256) void attn_greduce(
    const float* __restrict__ part, short* __restrict__ ctx)
{
    const int qb = blockIdx.x, h = blockIdx.y, b = blockIdx.z;
    const int tok0 = qb ? (SEQ - 64) : 0;
    const int t = threadIdx.x;
    const int qq = t >> 2, d0 = (t & 3) * 16;
    const float* base = part + ((size_t)(((b * NHEAD + h) * 2 + qb) * KSPL)) * 4224;

    float m = -1e30f;
    #pragma unroll 1
    for (int s = 0; s < KSPL; ++s)
        m = fmaxf(m, base[(size_t)s * 4224 + 4096 + qq]);
    float L = 0.f;
    float acc[16];
    #pragma unroll
    for (int i = 0; i < 16; ++i) acc[i] = 0.f;
    #pragma unroll 1
    for (int s = 0; s < KSPL; ++s) {
        const float* bp = base + (size_t)s * 4224;
        float w = __expf(bp[4096 + qq] - m);
        L += w * bp[4160 + qq];
        const float4* row = (const float4*)(bp + qq * 64 + d0);
        #pragma unroll
        for (int v4 = 0; v4 < 4; ++v4) {
            float4 val = row[v4];
            acc[v4 * 4 + 0] = fmaf(w, val.x, acc[v4 * 4 + 0]);
            acc[v4 * 4 + 1] = fmaf(w, val.y, acc[v4 * 4 + 1]);
            acc[v4 * 4 + 2] = fmaf(w, val.z, acc[v4 * 4 + 2]);
            acc[v4 * 4 + 3] = fmaf(w, val.w, acc[v4 * 4 + 3]);
        }
    }
    float inv = 1.f / L;
    short* dst = ctx + (size_t)(b * SEQ + tok0 + qq) * DIM + h * HDIM + d0;
    s16x8 o0, o1;
    #pragma unroll
    for (int i = 0; i < 8; ++i) { o0[i] = f2bf(acc[i] * inv); o1[i] = f2bf(acc[8 + i] * inv); }
    ((s16x8*)dst)[0] = o0;
    ((s16x8*)dst)[1] = o1;
}

// ---------------------------------------------------------------- column mean, stage 1
__global__ __launch_bounds__(256) void colsum1_kernel(
    const float* __restrict__ xln, float* __restrict__ partial)
{
    const int ch = blockIdx.x, b = blockIdx.y, t = threadIdx.x;
    const float* base = xln + ((size_t)b * SEQ + ch * 32) * DIM + t * 4;
    float4 acc = {0.f, 0.f, 0.f, 0.f};
    #pragma unroll 4
    for (int r = 0; r < 32; ++r) {
        float4 v = *(const float4*)(base + (size_t)r * DIM);
        acc.x += v.x; acc.y += v.y; acc.z += v.z; acc.w += v.w;
    }
    *(float4*)(partial + ((size_t)(b * 128 + ch)) * DIM + t * 4) = acc;
}

// ---------------------------------------------------------------- column mean, stage 2
__global__ __launch_bounds__(256) void colsum2_kernel(
    const float* __restrict__ partial, float* __restrict__ feats)
{
    const int b = blockIdx.x, t = threadIdx.x;
    float4 acc = {0.f, 0.f, 0.f, 0.f};
    #pragma unroll 1
    for (int ch = 0; ch < 128; ++ch) {
        float4 v = *(const float4*)(partial + ((size_t)(b * 128 + ch)) * DIM + t * 4);
        acc.x += v.x; acc.y += v.y; acc.z += v.z; acc.w += v.w;
    }
    const float is = 1.f / SEQ;
    float4 o = { acc.x * is, acc.y * is, acc.z * is, acc.w * is };
    *(float4*)(feats + (size_t)b * DIM + t * 4) = o;
}

// ---------------------------------------------------------------- normalize + project
__global__ __launch_bounds__(256) void head_kernel(
    const float* __restrict__ feats, const float* __restrict__ projW,
    const float* __restrict__ projb, float* __restrict__ out)
{
    __shared__ float f[DIM];
    __shared__ float slots[4];
    int b = blockIdx.x, t = threadIdx.x;
    float ss = 0.f;
    for (int i = t; i < DIM; i += 256) {
        float vv = feats[b * DIM + i];
        f[i] = vv;
        ss += vv * vv;
    }
    #pragma unroll
    for (int o = 32; o > 0; o >>= 1) ss += __shfl_xor(ss, o, 64);
    if ((t & 63) == 0) slots[t >> 6] = ss;
    __syncthreads();
    float nrm = sqrtf(slots[0] + slots[1] + slots[2] + slots[3]);
    float inv = 1.f / fmaxf(nrm, 1e-12f);
    for (int o = t; o < 512; o += 256) {
        float acc = 0.f;
        for (int d = 0; d < DIM; ++d)
            acc = fmaf(f[d], projW[(size_t)d * 512 + o], acc);
        out[b * 512 + o] = acc * inv + projb[o];
    }
}

// ---------------------------------------------------------------- launch
extern "C" void kernel_launch(void* const* d_in, const int* in_sizes, int n_in,
                              void* d_out, int out_size, void* d_ws, size_t ws_size,
                              hipStream_t stream)
{
    (void)in_sizes; (void)n_in; (void)out_size; (void)ws_size;
    const int*   ids   = (const int*)d_in[0];
    const int*   amask = (const int*)d_in[1];
    const int*   rnd   = (const int*)d_in[2];
    const float* emb   = (const float*)d_in[3];
    const float* Wq    = (const float*)d_in[4];
    const float* bq    = (const float*)d_in[5];
    const float* Wk    = (const float*)d_in[6];
    const float* bk    = (const float*)d_in[7];
    const float* Wv    = (const float*)d_in[8];
    const float* bv    = (const float*)d_in[9];
    const float* Wo    = (const float*)d_in[10];
    const float* bo    = (const float*)d_in[11];
    const float* ln1g  = (const float*)d_in[12];
    const float* ln1b  = (const float*)d_in[13];
    const float* W1    = (const float*)d_in[14];
    const float* b1    = (const float*)d_in[15];
    const float* W2    = (const float*)d_in[16];
    const float* b2    = (const float*)d_in[17];
    const float* ln2g  = (const float*)d_in[18];
    const float* ln2b  = (const float*)d_in[19];
    const float* lnfg  = (const float*)d_in[20];
    const float* lnfb  = (const float*)d_in[21];
    const float* projW = (const float*)d_in[22];
    const float* projb = (const float*)d_in[23];
    float* out = (float*)d_out;

    char* ws = (char*)d_ws;
    size_t off = 0;
    float* x    = (float*)(ws + off); off += (size_t)ROWS * DIM * 4;
    float* xn_f = (float*)(ws + off);
    short* xn_b = (short*)(ws + off); off += (size_t)ROWS * DIM * 4;
    short* qkv  = (short*)(ws + off); off += (size_t)ROWS * QKVLD * 2;   // 48 MB
    short* vT   = (short*)(ws + off); off += (size_t)ROWS * DIM * 2;     // 16 MB
    short* ctxb = (short*)(ws + off); off += (size_t)ROWS * DIM * 2;
    short* ffb  = (short*)(ws + off); off += (size_t)ROWS * FFDIM * 2;
    short* wt   = (short*)(ws + off); off += (size_t)FFDIM * DIM * 2;
    float* neg  = (float*)(ws + off); off += (size_t)ROWS * 4;
    float* bias3= (float*)(ws + off); off += (size_t)QKVLD * 4;
    float* feats= (float*)(ws + off); off += (size_t)BATCH * DIM * 4;
    float* part = (float*)(ws + off); off += (size_t)BATCH * NHEAD * 2 * KSPL * 4224 * 4;
    float* cpart= (float*)(ws + off); off += (size_t)BATCH * 128 * DIM * 4;
    // FF2 split-K fp32 partials (2 x 32 MB) alias the qkv+vT region (dead by FF2 time)
    float* ff2p = (float*)qkv;

    embed_kernel<<<ROWS, 256, 0, stream>>>(ids, emb, x);
    neg_kernel<<<(ROWS + 255) / 256, 256, 0, stream>>>(amask, neg);

    for (int l = 0; l < NLAYER; ++l) {
        ln_kernel<1><<<ROWS, 256, 0, stream>>>(x, ln1g + l * DIM, ln1b + l * DIM, xn_b);

        // fused QKV: Wt rows [0,1024)=Wq^T, [1024,2048)=Wk^T, [2048,3072)=Wv^T
        wconv_kernel<<<dim3(DIM/32, DIM/32), 256, 0, stream>>>(Wq + (size_t)l*DIM*DIM, wt,               DIM, DIM);
        wconv_kernel<<<dim3(DIM/32, DIM/32), 256, 0, stream>>>(Wk + (size_t)l*DIM*DIM, wt + 1024*1024,   DIM, DIM);
        wconv_kernel<<<dim3(DIM/32, DIM/32), 256, 0, stream>>>(Wv + (size_t)l*DIM*DIM, wt + 2*1024*1024, DIM, DIM);
        biaspack_kernel<<<QKVLD/256, 256, 0, stream>>>(bq + l*DIM, bk + l*DIM, bv + l*DIM, bias3);
        gemm256_kernel<0><<<dim3(ROWS/256, QKVLD/256), 512, 0, stream>>>(xn_b, wt, bias3, nullptr, qkv, ROWS, QKVLD, DIM, DIM);

        vtrans_kernel<<<dim3(SEQ/64, NHEAD, BATCH), 256, 0, stream>>>(qkv, vT);

        attn_global_mfma<<<dim3(2 * KSPL, NHEAD, BATCH), 256, 0, stream>>>(qkv, vT, neg, part);
        attn_middle_mfma<<<dim3(NMID, NHEAD, BATCH), 256, 0, stream>>>(qkv, vT, neg, rnd, ctxb);
        attn_greduce<<<dim3(2, NHEAD, BATCH), 256, 0, stream>>>(part, ctxb);

        wconv_kernel<<<dim3(DIM/32, DIM/32), 256, 0, stream>>>(Wo + (size_t)l*DIM*DIM, wt, DIM, DIM);
        gemm_kernel<2><<<dim3(ROWS/128, DIM/128), 256, 0, stream>>>(ctxb, wt, bo + l*DIM, x, x, ROWS, DIM, DIM, DIM);

        ln_kernel<1><<<ROWS, 256, 0, stream>>>(x, ln2g + l * DIM, ln2b + l * DIM, xn_b);

        wconv_kernel<<<dim3(DIM/32, FFDIM/32), 256, 0, stream>>>(W1 + (size_t)l*DIM*FFDIM, wt, DIM, FFDIM);
        gemm256_kernel<1><<<dim3(ROWS/256, FFDIM/256), 512, 0, stream>>>(xn_b, wt, b1 + l*FFDIM, nullptr, ffb, ROWS, FFDIM, DIM, DIM);
        wconv_kernel<<<dim3(FFDIM/32, DIM/32), 256, 0, stream>>>(W2 + (size_t)l*FFDIM*DIM, wt, FFDIM, DIM);
        // FF2: split-K x2 -> fp32 partials -> fused reduce (+bias +residual into x)
        gemm256_kernel<3><<<dim3(ROWS/256, DIM/256, 2), 512, 0, stream>>>(ffb, wt, nullptr, nullptr, ff2p, ROWS, DIM, FFDIM, FFDIM/2);
        kred_kernel<<<ROWS, 256, 0, stream>>>(ff2p, b2 + l*DIM, x);
    }

    ln_kernel<0><<<ROWS, 256, 0, stream>>>(x, lnfg, lnfb, xn_f);
    colsum1_kernel<<<dim3(SEQ/32, BATCH), 256, 0, stream>>>(xn_f, cpart);
    colsum2_kernel<<<BATCH, 256, 0, stream>>>(cpart, feats);
    head_kernel<<<BATCH, 256, 0, stream>>>(feats, projW, projb, out);
}